// Round 2
// baseline (167.276 us; speedup 1.0000x reference)
//
#include <hip/hip_runtime.h>

#define HID 512
#define HEADS 8
#define HD 64
#define BATCH 2
#define SEQ 384
#define MROWS (BATCH * SEQ)  // 768
// 2-section packs: [Ah | Al] and [Bh | Bl], 16 base k-tiles each (K=512)
#define APACK_S8 (48 * 32 * 64)   // 98304 s8-chunks per packed A
#define BPACK_S8 (32 * 32 * 64)   // 65536 s8-chunks per packed B

// 2*log2(e): Eq = exp2(C1 * qW) == exp(2*qW)
#define C1 2.8853900817779268f
// log2(e)/8: softmax exponent scale (energy = raw/8)
#define SSCL 0.18033688011112043f

typedef __attribute__((ext_vector_type(8))) short s8v;   // 8 bf16 (4 VGPR)
typedef __attribute__((ext_vector_type(4))) float f4v;   // MFMA acc

__device__ __forceinline__ unsigned short bf16_rne(float x) {
    union { float f; unsigned u; } v; v.f = x;
    unsigned r = v.u + 0x7FFFu + ((v.u >> 16) & 1u);
    return (unsigned short)(r >> 16);
}
__device__ __forceinline__ float bf16_val(unsigned short h) {
    union { float f; unsigned u; } v; v.u = ((unsigned)h) << 16; return v.f;
}

// ---------------------------------------------------------------------------
// Pack A [768x512 f32] -> [Ah | Al] bf16 in MFMA swizzle:
// s8 index (mt*32 + sec*16 + kt)*64 + lane, lane = (m&15) | ((g&3)<<4)
// ---------------------------------------------------------------------------
__device__ __forceinline__ void pack_a_one(const float* __restrict__ src,
                                           s8v* __restrict__ dst, int rem)
{
    int g = rem & 63, m = rem >> 6;           // c = 8g .. 8g+7
    const float4* sp = (const float4*)(src + (size_t)m * HID + g * 8);
    float4 v0 = sp[0], v1 = sp[1];
    float vals[8] = {v0.x, v0.y, v0.z, v0.w, v1.x, v1.y, v1.z, v1.w};
    s8v hi, lo;
    #pragma unroll
    for (int j = 0; j < 8; ++j) {
        unsigned short h = bf16_rne(vals[j]);
        hi[j] = (short)h;
        lo[j] = (short)bf16_rne(vals[j] - bf16_val(h));
    }
    int mt = m >> 4, kt = g >> 2;
    int lanei = (m & 15) | ((g & 3) << 4);
    size_t base = ((size_t)mt * 32) * 64 + lanei;
    dst[base + (size_t)kt * 64]        = hi;  // sec0: Ah
    dst[base + (size_t)(16 + kt) * 64] = lo;  // sec1: Al
}

// ---------------------------------------------------------------------------
// Pack W [512x512 f32, (k,n)] -> [Bh | Bl] in MFMA swizzle
// ---------------------------------------------------------------------------
__device__ __forceinline__ void pack_w_store(s8v* __restrict__ dst,
                                             const float vals[8], int kg, int n)
{
    s8v hi, lo;
    #pragma unroll
    for (int j = 0; j < 8; ++j) {
        unsigned short h = bf16_rne(vals[j]);
        hi[j] = (short)h;
        lo[j] = (short)bf16_rne(vals[j] - bf16_val(h));
    }
    int nt = n >> 4, kt = kg >> 2;
    int lanei = (n & 15) | ((kg & 3) << 4);
    size_t base = ((size_t)nt * 32) * 64 + lanei;
    dst[base + (size_t)kt * 64]        = hi;  // sec0: Bh
    dst[base + (size_t)(16 + kt) * 64] = lo;  // sec1: Bl
}

__device__ __forceinline__ void pack_w_one(const float* __restrict__ W,
                                           s8v* __restrict__ dst, int rem)
{
    int kg = rem >> 9, n = rem & 511;         // k = 8kg .. 8kg+7
    float vals[8];
    #pragma unroll
    for (int j = 0; j < 8; ++j)
        vals[j] = W[(size_t)(kg * 8 + j) * HID + n];   // coalesced across n
    pack_w_store(dst, vals, kg, n);
}

// fold Wbig(512x512) @ blockdiag(Wsmall 64x64) on the fly, then pack
__device__ __forceinline__ void fold_pack_w_one(const float* __restrict__ Wbig,
                                                const float* __restrict__ Wsmall,
                                                s8v* __restrict__ dst, int rem)
{
    int kg = __builtin_amdgcn_readfirstlane(rem >> 9);
    int n  = rem & 511;
    int h  = __builtin_amdgcn_readfirstlane(n >> 6);
    int d  = n & 63;
    const float* wr = Wbig + (size_t)(kg * 8) * HID + h * HD;
    float acc[8] = {0.f, 0.f, 0.f, 0.f, 0.f, 0.f, 0.f, 0.f};
    #pragma unroll 8
    for (int t = 0; t < 64; ++t) {
        float wv = Wsmall[t * 64 + d];      // coalesced across lanes
        #pragma unroll
        for (int j = 0; j < 8; ++j)
            acc[j] = fmaf(wr[(size_t)j * HID + t], wv, acc[j]);  // uniform
    }
    pack_w_store(dst, acc, kg, n);
}

// ---------------------------------------------------------------------------
// ONE launch for all prep+pack work (no internal dependencies):
// [0,576): A packs q,k,v | [576,704): Wv | [704,832): Wo
// [832,960): fold(Wq,Ww) | [960,1088): fold(Wk,Wu) | [1088]: biases + vv2
// ---------------------------------------------------------------------------
__global__ __launch_bounds__(256) void pack_all_kernel(
    const float* __restrict__ q, const float* __restrict__ k, const float* __restrict__ v,
    const float* __restrict__ Wq, const float* __restrict__ bq,
    const float* __restrict__ Wk, const float* __restrict__ bk,
    const float* __restrict__ Wv, const float* __restrict__ Wo,
    const float* __restrict__ Ww, const float* __restrict__ bw,
    const float* __restrict__ Wu, const float* __restrict__ bu,
    const float* __restrict__ vv,
    s8v* __restrict__ Aq, s8v* __restrict__ Ak, s8v* __restrict__ Av,
    s8v* __restrict__ Bq, s8v* __restrict__ Bk, s8v* __restrict__ Bv, s8v* __restrict__ Bo,
    float* __restrict__ bqe, float* __restrict__ bke, float* __restrict__ vv2)
{
    int bx = blockIdx.x, tid = threadIdx.x;
    if (bx < 576) {
        int p = bx / 192;
        int rem = (bx % 192) * 256 + tid;
        const float* src = (p == 0) ? q : (p == 1) ? k : v;
        s8v* dst = (p == 0) ? Aq : (p == 1) ? Ak : Av;
        pack_a_one(src, dst, rem);
    } else if (bx < 704) {
        pack_w_one(Wv, Bv, (bx - 576) * 256 + tid);
    } else if (bx < 832) {
        pack_w_one(Wo, Bo, (bx - 704) * 256 + tid);
    } else if (bx < 960) {
        fold_pack_w_one(Wq, Ww, Bq, (bx - 832) * 256 + tid);
    } else if (bx < 1088) {
        fold_pack_w_one(Wk, Wu, Bk, (bx - 960) * 256 + tid);
    } else {
        for (int i = tid; i < 1088; i += 256) {
            if (i < 512) {
                int h = i >> 6, j = i & 63;
                float s = bw[j];
                for (int t = 0; t < 64; ++t) s = fmaf(bq[h * 64 + t], Ww[t * 64 + j], s);
                bqe[i] = s;
            } else if (i < 1024) {
                int n = i - 512, h = n >> 6, j = n & 63;
                float s = bu[j];
                for (int t = 0; t < 64; ++t) s = fmaf(bk[h * 64 + t], Wu[t * 64 + j], s);
                bke[n] = s;
            } else {
                vv2[i - 1024] = -2.0f * vv[i - 1024];
            }
        }
    }
}

// ---------------------------------------------------------------------------
// MFMA GEMM: FOUR waves per block (256 thr), 32x32 tile (2x2 MFMA 16x16x32),
// K-SPLIT across waves: wave w accumulates base k-tiles 4w..4w+3, then a
// single 16KB LDS exchange + one barrier; each wave reduces and writes one
// acc quadrant.
// 3-term bf16 split per base k-tile: AhBh + AhBl + AlBh (12 MFMA / 8 loads)
// MODE 0: plain  MODE 1: exp2(C1*y)  MODE 2: exp2 + transposed-packed Ek4
// ---------------------------------------------------------------------------
struct Frag { s8v ah0, al0, ah1, al1, bh0, bl0, bh1, bl1; };

__device__ __forceinline__ void load_frag(Frag& f,
    const s8v* __restrict__ a0, const s8v* __restrict__ a1,
    const s8v* __restrict__ b0, const s8v* __restrict__ b1, int kt)
{
    int oh = kt * 64, ol = (16 + kt) * 64;
    f.ah0 = a0[oh]; f.al0 = a0[ol];
    f.ah1 = a1[oh]; f.al1 = a1[ol];
    f.bh0 = b0[oh]; f.bl0 = b0[ol];
    f.bh1 = b1[oh]; f.bl1 = b1[ol];
}

__device__ __forceinline__ void compute_frag(f4v& acc00, f4v& acc01,
                                             f4v& acc10, f4v& acc11, const Frag& f)
{
    acc00 = __builtin_amdgcn_mfma_f32_16x16x32_bf16(f.ah0, f.bh0, acc00, 0, 0, 0);
    acc01 = __builtin_amdgcn_mfma_f32_16x16x32_bf16(f.ah0, f.bh1, acc01, 0, 0, 0);
    acc10 = __builtin_amdgcn_mfma_f32_16x16x32_bf16(f.ah1, f.bh0, acc10, 0, 0, 0);
    acc11 = __builtin_amdgcn_mfma_f32_16x16x32_bf16(f.ah1, f.bh1, acc11, 0, 0, 0);
    acc00 = __builtin_amdgcn_mfma_f32_16x16x32_bf16(f.ah0, f.bl0, acc00, 0, 0, 0);
    acc01 = __builtin_amdgcn_mfma_f32_16x16x32_bf16(f.ah0, f.bl1, acc01, 0, 0, 0);
    acc10 = __builtin_amdgcn_mfma_f32_16x16x32_bf16(f.ah1, f.bl0, acc10, 0, 0, 0);
    acc11 = __builtin_amdgcn_mfma_f32_16x16x32_bf16(f.ah1, f.bl1, acc11, 0, 0, 0);
    acc00 = __builtin_amdgcn_mfma_f32_16x16x32_bf16(f.al0, f.bh0, acc00, 0, 0, 0);
    acc01 = __builtin_amdgcn_mfma_f32_16x16x32_bf16(f.al0, f.bh1, acc01, 0, 0, 0);
    acc10 = __builtin_amdgcn_mfma_f32_16x16x32_bf16(f.al1, f.bh0, acc10, 0, 0, 0);
    acc11 = __builtin_amdgcn_mfma_f32_16x16x32_bf16(f.al1, f.bh1, acc11, 0, 0, 0);
}

template <int MODE>
__device__ __forceinline__ void mfma_gemm_body(
    const s8v* __restrict__ Ap, const s8v* __restrict__ Bp,
    const float* __restrict__ bias, float* __restrict__ out,
    int mt0, int nt0)
{
    __shared__ f4v red[4][4][64];   // [src wave][acc quadrant][lane] = 16 KB

    int tid  = threadIdx.x;
    int wave = __builtin_amdgcn_readfirstlane(tid >> 6);
    int lane = tid & 63;

    const s8v* a0p = Ap + (size_t)(mt0 * 32) * 64 + lane;
    const s8v* a1p = a0p + (size_t)32 * 64;
    const s8v* b0p = Bp + (size_t)(nt0 * 32) * 64 + lane;
    const s8v* b1p = b0p + (size_t)32 * 64;

    f4v acc00 = {0.f, 0.f, 0.f, 0.f};
    f4v acc01 = {0.f, 0.f, 0.f, 0.f};
    f4v acc10 = {0.f, 0.f, 0.f, 0.f};
    f4v acc11 = {0.f, 0.f, 0.f, 0.f};

    // wave w owns base k-tiles 4w .. 4w+3 (each with hi+lo sections)
    int kt0 = wave * 4;
    Frag X, Y;
    load_frag(X, a0p, a1p, b0p, b1p, kt0);
    load_frag(Y, a0p, a1p, b0p, b1p, kt0 + 1);
    compute_frag(acc00, acc01, acc10, acc11, X);
    load_frag(X, a0p, a1p, b0p, b1p, kt0 + 2);
    compute_frag(acc00, acc01, acc10, acc11, Y);
    load_frag(Y, a0p, a1p, b0p, b1p, kt0 + 3);
    compute_frag(acc00, acc01, acc10, acc11, X);
    compute_frag(acc00, acc01, acc10, acc11, Y);

    red[wave][0][lane] = acc00;
    red[wave][1][lane] = acc01;
    red[wave][2][lane] = acc10;
    red[wave][3][lane] = acc11;
    __syncthreads();

    // wave w reduces + writes acc quadrant w:
    // 0 -> (row0,col0)  1 -> (row0,col1)  2 -> (row1,col0)  3 -> (row1,col1)
    f4v s = red[0][wave][lane] + red[1][wave][lane]
          + red[2][wave][lane] + red[3][wave][lane];

    // C/D layout: row = quad*4 + reg, col = lane&15.
    int quad = lane >> 4, c16 = lane & 15;
    int R0 = mt0 * 16 + quad * 4 + (wave >> 1) * 16;
    int C  = nt0 * 16 + c16 + (wave & 1) * 16;
    float biasC = bias[C];

    #pragma unroll
    for (int r = 0; r < 4; ++r) {
        float yy = s[r] + biasC;
        if (MODE != 0) yy = __builtin_amdgcn_exp2f(C1 * yy);
        if (MODE == 2) {
            int ROW = R0 + r;
            int b2 = ROW / SEQ, kk = ROW - b2 * SEQ;
            int hh = C >> 6, dd = C & 63;
            out[(((size_t)((b2 * 8 + hh) * 16 + (dd >> 2)) * SEQ + kk) << 2)
                + (dd & 3)] = yy;
        } else {
            out[(size_t)(R0 + r) * HID + C] = yy;
        }
    }
}

__global__ __launch_bounds__(256) void proj3_mfma_kernel(
    const s8v* __restrict__ Aq, const s8v* __restrict__ Ak, const s8v* __restrict__ Av,
    const s8v* __restrict__ Bq, const s8v* __restrict__ Bk, const s8v* __restrict__ Bv,
    const float* __restrict__ bqe, const float* __restrict__ bke, const float* __restrict__ bv,
    float* __restrict__ Eq, float* __restrict__ Ek4, float* __restrict__ V)
{
    int p = blockIdx.z;
    int mt0 = blockIdx.x * 2, nt0 = blockIdx.y * 2;
    if (p == 0)      mfma_gemm_body<1>(Aq, Bq, bqe, Eq,  mt0, nt0);
    else if (p == 1) mfma_gemm_body<2>(Ak, Bk, bke, Ek4, mt0, nt0);
    else             mfma_gemm_body<0>(Av, Bv, bv,  V,   mt0, nt0);
}

__global__ __launch_bounds__(256) void out_mfma_kernel(
    const s8v* __restrict__ Ax, const s8v* __restrict__ Bo,
    const float* __restrict__ bo, float* __restrict__ out)
{
    mfma_gemm_body<0>(Ax, Bo, bo, out, blockIdx.x * 2, blockIdx.y * 2);
}

// ---------------------------------------------------------------------------
// attention (R12: cross-wave LDS sharing of Ek and V):
// 2 q-rows per wave, 768 blocks = 3 blocks/CU. All 4 waves of a block share
// one bh slice, so Ek chunks (24 KB) and V tiles (16 KB) are staged once per
// BLOCK into a unioned LDS buffer instead of streamed 4x per block from L2
// (604 MB -> ~150 MB of L2 reads). T14-style reg staging: issue global loads
// early, compute on the current LDS buffer, then barrier + ds_write + barrier
// so the HBM/L2 latency hides under the trans-heavy energy phase.
// XCD swizzle: xcd = blk & 7; each XCD handles exactly 2 bh slices.
// Eq/vv2 wave-uniform -> scalar; epilogue packs X directly into Ax.
// ---------------------------------------------------------------------------
__global__ __launch_bounds__(256, 3) void attn_kernel(
    const float* __restrict__ Eq, const float* __restrict__ Ek4,
    const float* __restrict__ V, const float* __restrict__ vv2,
    float* __restrict__ attnOut, s8v* __restrict__ Ax)
{
    __shared__ float4 shbuf[4 * SEQ];   // 24 KB: Ek chunk (energy) U V tile
    __shared__ float2 aP[4][SEQ];       // 12 KB

    int blk = blockIdx.x;
    int xcd = blk & 7, slot = blk >> 3;       // slot in [0,96)
    int part = slot / 48, qblk = slot % 48;
    int bh = xcd * 2 + part;
    int b = bh >> 3, h = bh & 7;
    int tid = threadIdx.x;
    int wave = __builtin_amdgcn_readfirstlane(tid >> 6);
    int lane = tid & 63;
    int q0 = qblk * 8 + wave * 2, q1 = q0 + 1;

    const float* eq0 = Eq + (size_t)(b * SEQ + q0) * HID + h * HD;  // uniform
    const float* eq1 = eq0 + HID;
    const float4* ek4g = (const float4*)Ek4 + (size_t)bh * 16 * SEQ;

    float e0[6], e1[6];
    #pragma unroll
    for (int t = 0; t < 6; ++t) { e0[t] = 0.f; e1[t] = 0.f; }

    // prologue: stage Ek chunk 0 (1536 float4 = 24 KB, 6 per thread)
    float4 st[6];
    #pragma unroll
    for (int r = 0; r < 6; ++r) st[r] = ek4g[tid + r * 256];
    #pragma unroll
    for (int r = 0; r < 6; ++r) shbuf[tid + r * 256] = st[r];
    __syncthreads();

    #pragma unroll 1
    for (int c = 0; c < 4; ++c) {
        // issue next chunk's global loads early (latency hides under compute)
        if (c < 3) {
            const float4* src = ek4g + (size_t)(c + 1) * 4 * SEQ;
            #pragma unroll
            for (int r = 0; r < 6; ++r) st[r] = src[tid + r * 256];
        }
        float g0[16], g1[16], w[16];
        #pragma unroll
        for (int j = 0; j < 16; ++j) {
            g0[j] = eq0[c * 16 + j];   // wave-uniform -> s_load
            g1[j] = eq1[c * 16 + j];
            w[j]  = vv2[c * 16 + j];
        }
        #pragma unroll
        for (int kt = 0; kt < 6; ++kt) {
            float4 k0 = shbuf[0 * SEQ + kt * 64 + lane];
            float4 k1 = shbuf[1 * SEQ + kt * 64 + lane];
            float4 k2 = shbuf[2 * SEQ + kt * 64 + lane];
            float4 k3 = shbuf[3 * SEQ + kt * 64 + lane];
            float r0 = e0[kt], r1 = e1[kt];
            #define EN(J, KV)                                                      \
            {                                                                      \
                float t0 = __builtin_amdgcn_rcpf(fmaf(g0[J], (KV), 1.f));          \
                float t1 = __builtin_amdgcn_rcpf(fmaf(g1[J], (KV), 1.f));          \
                r0 = fmaf(w[J], t0, r0);                                           \
                r1 = fmaf(w[J], t1, r1);                                           \
            }
            EN(0,  k0.x) EN(1,  k0.y) EN(2,  k0.z) EN(3,  k0.w)
            EN(4,  k1.x) EN(5,  k1.y) EN(6,  k1.z) EN(7,  k1.w)
            EN(8,  k2.x) EN(9,  k2.y) EN(10, k2.z) EN(11, k2.w)
            EN(12, k3.x) EN(13, k3.y) EN(14, k3.z) EN(15, k3.w)
            #undef EN
            e0[kt] = r0; e1[kt] = r1;
        }
        if (c < 3) {
            __syncthreads();   // all waves done reading chunk c
            #pragma unroll
            for (int r = 0; r < 6; ++r) shbuf[tid + r * 256] = st[r];
            __syncthreads();   // chunk c+1 ready
        }
    }

    // Issue V tile 0 global loads now (1024 float4 = 16 KB, 4 per thread);
    // latency hides under the register-only softmax.
    int ko = lane >> 4, d4p = lane & 15;
    const float4* vtg = (const float4*)V + (size_t)b * SEQ * (HID / 4) + h * 16;
    float4 vt[4];
    #pragma unroll
    for (int r = 0; r < 4; ++r) {
        int idx = tid + r * 256;
        vt[r] = vtg[(size_t)(idx >> 4) * (HID / 4) + (idx & 15)];
    }

    // softmax over k (384 = 6 tiles x 64 lanes), registers only
    float m0 = e0[0], m1 = e1[0];
    #pragma unroll
    for (int t = 1; t < 6; ++t) { m0 = fmaxf(m0, e0[t]); m1 = fmaxf(m1, e1[t]); }
    #pragma unroll
    for (int off = 1; off < 64; off <<= 1) {
        m0 = fmaxf(m0, __shfl_xor(m0, off));
        m1 = fmaxf(m1, __shfl_xor(m1, off));
    }
    float a0[6], a1[6], s0 = 0.f, s1 = 0.f;
    #pragma unroll
    for (int t = 0; t < 6; ++t) {
        a0[t] = __builtin_amdgcn_exp2f((e0[t] - m0) * SSCL); s0 += a0[t];
        a1[t] = __builtin_amdgcn_exp2f((e1[t] - m1) * SSCL); s1 += a1[t];
    }
    #pragma unroll
    for (int off = 1; off < 64; off <<= 1) {
        s0 += __shfl_xor(s0, off);
        s1 += __shfl_xor(s1, off);
    }
    float z0 = __builtin_amdgcn_rcpf(s0), z1 = __builtin_amdgcn_rcpf(s1);

    size_t abase = (size_t)bh * SEQ * SEQ + (size_t)q0 * SEQ;
    #pragma unroll
    for (int t = 0; t < 6; ++t) {
        float v0 = a0[t] * z0, v1 = a1[t] * z1;
        attnOut[abase + t * 64 + lane] = v0;
        attnOut[abase + SEQ + t * 64 + lane] = v1;
        aP[wave][t * 64 + lane] = make_float2(v0, v1);
    }

    __syncthreads();   // all Ek reads done -> safe to overwrite shbuf with V
    #pragma unroll
    for (int r = 0; r < 4; ++r) shbuf[tid + r * 256] = vt[r];
    __syncthreads();   // V tile 0 ready

    // attn @ V: lane = ko*16 + d4p; V tiles from LDS (shared by all 4 waves),
    // next tile reg-staged during current tile's compute.
    float4 x0 = make_float4(0.f, 0.f, 0.f, 0.f);
    float4 x1 = make_float4(0.f, 0.f, 0.f, 0.f);
    #pragma unroll 1
    for (int t = 0; t < 6; ++t) {
        if (t < 5) {
            #pragma unroll
            for (int r = 0; r < 4; ++r) {
                int idx = tid + r * 256;
                vt[r] = vtg[(size_t)((t + 1) * 64 + (idx >> 4)) * (HID / 4) + (idx & 15)];
            }
        }
        #pragma unroll
        for (int i = 0; i < 16; ++i) {
            int kk = ko + i * 4;
            float4 v = shbuf[kk * 16 + d4p];
            float2 a = aP[wave][t * 64 + kk];
            x0.x = fmaf(a.x, v.x, x0.x); x0.y = fmaf(a.x, v.y, x0.y);
            x0.z = fmaf(a.x, v.z, x0.z); x0.w = fmaf(a.x, v.w, x0.w);
            x1.x = fmaf(a.y, v.x, x1.x); x1.y = fmaf(a.y, v.y, x1.y);
            x1.z = fmaf(a.y, v.z, x1.z); x1.w = fmaf(a.y, v.w, x1.w);
        }
        if (t < 5) {
            __syncthreads();   // all waves done reading tile t
            #pragma unroll
            for (int r = 0; r < 4; ++r) shbuf[tid + r * 256] = vt[r];
            __syncthreads();   // tile t+1 ready
        }
    }
    #pragma unroll
    for (int off = 16; off < 64; off <<= 1) {
        x0.x += __shfl_xor(x0.x, off); x0.y += __shfl_xor(x0.y, off);
        x0.z += __shfl_xor(x0.z, off); x0.w += __shfl_xor(x0.w, off);
        x1.x += __shfl_xor(x1.x, off); x1.y += __shfl_xor(x1.y, off);
        x1.z += __shfl_xor(x1.z, off); x1.w += __shfl_xor(x1.w, off);
    }

    // Pack X rows q0/q1 (this head's 64 cols) straight into Ax.
    // Lanes 0..15 hold the full row as float4; chunk u (8 floats) = lanes {2u,2u+1}.
    if (ko == 0) {
        float4 p0, p1;
        p0.x = __shfl_xor(x0.x, 1); p0.y = __shfl_xor(x0.y, 1);
        p0.z = __shfl_xor(x0.z, 1); p0.w = __shfl_xor(x0.w, 1);
        p1.x = __shfl_xor(x1.x, 1); p1.y = __shfl_xor(x1.y, 1);
        p1.z = __shfl_xor(x1.z, 1); p1.w = __shfl_xor(x1.w, 1);
        float vals[8];
        int row;
        if ((lane & 1) == 0) {
            vals[0] = x0.x; vals[1] = x0.y; vals[2] = x0.z; vals[3] = x0.w;
            vals[4] = p0.x; vals[5] = p0.y; vals[6] = p0.z; vals[7] = p0.w;
            row = b * SEQ + q0;
        } else {
            vals[0] = p1.x; vals[1] = p1.y; vals[2] = p1.z; vals[3] = p1.w;
            vals[4] = x1.x; vals[5] = x1.y; vals[6] = x1.z; vals[7] = x1.w;
            row = b * SEQ + q1;
        }
        int g = h * 8 + (lane >> 1);   // global 8-col group
        s8v hi, lo;
        #pragma unroll
        for (int j = 0; j < 8; ++j) {
            unsigned short hh = bf16_rne(vals[j]);
            hi[j] = (short)hh;
            lo[j] = (short)bf16_rne(vals[j] - bf16_val(hh));
        }
        int mt = row >> 4, kt2 = g >> 2;
        int lanei = (row & 15) | ((g & 3) << 4);
        size_t base = ((size_t)mt * 32) * 64 + lanei;
        Ax[base + (size_t)kt2 * 64]        = hi;
        Ax[base + (size_t)(16 + kt2) * 64] = lo;
    }
}

// ---------------------------------------------------------------------------
extern "C" void kernel_launch(void* const* d_in, const int* in_sizes, int n_in,
                              void* d_out, int out_size, void* d_ws, size_t ws_size,
                              hipStream_t stream)
{
    const float* query = (const float*)d_in[0];
    const float* key   = (const float*)d_in[1];
    const float* value = (const float*)d_in[2];
    const float* Wq = (const float*)d_in[3];
    const float* bq = (const float*)d_in[4];
    const float* Wk = (const float*)d_in[5];
    const float* bk = (const float*)d_in[6];
    const float* Wv = (const float*)d_in[7];
    const float* bv = (const float*)d_in[8];
    const float* Ww = (const float*)d_in[9];
    const float* bw = (const float*)d_in[10];
    const float* Wu = (const float*)d_in[11];
    const float* bu = (const float*)d_in[12];
    const float* vv = (const float*)d_in[13];
    const float* Wo = (const float*)d_in[14];
    const float* bo = (const float*)d_in[15];

    float* out_x    = (float*)d_out;                 // [2,384,512]
    float* out_attn = out_x + (size_t)MROWS * HID;   // [2,8,384,384]

    float* ws  = (float*)d_ws;
    float* bqe = ws;                 // 512
    float* bke = bqe + 512;          // 512
    float* vv2 = bke + 512;          // 64
    float* EqB = vv2 + 64;           // 393216
    float* Ek4 = EqB + 393216;       // 393216 (transposed-packed)
    float* Vw  = Ek4 + 393216;       // 393216

    s8v* packs = (s8v*)(Vw + 393216);        // 16B-aligned
    s8v* Aq = packs;                          // APACK_S8 each
    s8v* Ak = Aq + APACK_S8;
    s8v* Av = Ak + APACK_S8;
    s8v* Ax = Av + APACK_S8;
    s8v* Bq = Ax + APACK_S8;                  // BPACK_S8 each
    s8v* Bk = Bq + BPACK_S8;
    s8v* Bv = Bk + BPACK_S8;
    s8v* Bo = Bv + BPACK_S8;

    pack_all_kernel<<<dim3(1089), 256, 0, stream>>>(
        query, key, value,
        Wq, bq, Wk, bk, Wv, Wo, Ww, bw, Wu, bu, vv,
        Aq, Ak, Av, Bq, Bk, Bv, Bo,
        bqe, bke, vv2);
    proj3_mfma_kernel<<<dim3(24, 16, 3), 256, 0, stream>>>(Aq, Ak, Av, Bq, Bk, Bv,
                                                           bqe, bke, bv,
                                                           EqB, Ek4, Vw);
    attn_kernel<<<dim3(768), 256, 0, stream>>>(EqB, Ek4, Vw, vv2, out_attn, Ax);
    out_mfma_kernel<<<dim3(24, 16), 256, 0, stream>>>(Ax, Bo, bo, out_x);
}

// Round 3
// 145.839 us; speedup vs baseline: 1.1470x; 1.1470x over previous
//
#include <hip/hip_runtime.h>

#define HID 512
#define HEADS 8
#define HD 64
#define BATCH 2
#define SEQ 384
#define MROWS (BATCH * SEQ)  // 768
// 2-section packs: [Ah | Al] and [Bh | Bl], 16 base k-tiles each (K=512)
#define APACK_S8 (48 * 32 * 64)   // 98304 s8-chunks per packed A
#define BPACK_S8 (32 * 32 * 64)   // 65536 s8-chunks per packed B

// 2*log2(e): Eq = exp2(C1 * qW) == exp(2*qW)
#define C1 2.8853900817779268f
// log2(e)/8: softmax exponent scale (energy = raw/8)
#define SSCL 0.18033688011112043f

typedef __attribute__((ext_vector_type(8))) short s8v;   // 8 bf16 (4 VGPR)
typedef __attribute__((ext_vector_type(4))) float f4v;   // MFMA acc

__device__ __forceinline__ unsigned short bf16_rne(float x) {
    union { float f; unsigned u; } v; v.f = x;
    unsigned r = v.u + 0x7FFFu + ((v.u >> 16) & 1u);
    return (unsigned short)(r >> 16);
}
__device__ __forceinline__ float bf16_val(unsigned short h) {
    union { float f; unsigned u; } v; v.u = ((unsigned)h) << 16; return v.f;
}

// ---------------------------------------------------------------------------
// Pack A [768x512 f32] -> [Ah | Al] bf16 in MFMA swizzle:
// s8 index (mt*32 + sec*16 + kt)*64 + lane, lane = (m&15) | ((g&3)<<4)
// ---------------------------------------------------------------------------
__device__ __forceinline__ void pack_a_one(const float* __restrict__ src,
                                           s8v* __restrict__ dst, int rem)
{
    int g = rem & 63, m = rem >> 6;           // c = 8g .. 8g+7
    const float4* sp = (const float4*)(src + (size_t)m * HID + g * 8);
    float4 v0 = sp[0], v1 = sp[1];
    float vals[8] = {v0.x, v0.y, v0.z, v0.w, v1.x, v1.y, v1.z, v1.w};
    s8v hi, lo;
    #pragma unroll
    for (int j = 0; j < 8; ++j) {
        unsigned short h = bf16_rne(vals[j]);
        hi[j] = (short)h;
        lo[j] = (short)bf16_rne(vals[j] - bf16_val(h));
    }
    int mt = m >> 4, kt = g >> 2;
    int lanei = (m & 15) | ((g & 3) << 4);
    size_t base = ((size_t)mt * 32) * 64 + lanei;
    dst[base + (size_t)kt * 64]        = hi;  // sec0: Ah
    dst[base + (size_t)(16 + kt) * 64] = lo;  // sec1: Al
}

// ---------------------------------------------------------------------------
// Pack W [512x512 f32, (k,n)] -> [Bh | Bl] in MFMA swizzle
// ---------------------------------------------------------------------------
__device__ __forceinline__ void pack_w_store(s8v* __restrict__ dst,
                                             const float vals[8], int kg, int n)
{
    s8v hi, lo;
    #pragma unroll
    for (int j = 0; j < 8; ++j) {
        unsigned short h = bf16_rne(vals[j]);
        hi[j] = (short)h;
        lo[j] = (short)bf16_rne(vals[j] - bf16_val(h));
    }
    int nt = n >> 4, kt = kg >> 2;
    int lanei = (n & 15) | ((kg & 3) << 4);
    size_t base = ((size_t)nt * 32) * 64 + lanei;
    dst[base + (size_t)kt * 64]        = hi;  // sec0: Bh
    dst[base + (size_t)(16 + kt) * 64] = lo;  // sec1: Bl
}

__device__ __forceinline__ void pack_w_one(const float* __restrict__ W,
                                           s8v* __restrict__ dst, int rem)
{
    int kg = rem >> 9, n = rem & 511;         // k = 8kg .. 8kg+7
    float vals[8];
    #pragma unroll
    for (int j = 0; j < 8; ++j)
        vals[j] = W[(size_t)(kg * 8 + j) * HID + n];   // coalesced across n
    pack_w_store(dst, vals, kg, n);
}

// fold Wbig(512x512) @ blockdiag(Wsmall 64x64) on the fly, then pack
__device__ __forceinline__ void fold_pack_w_one(const float* __restrict__ Wbig,
                                                const float* __restrict__ Wsmall,
                                                s8v* __restrict__ dst, int rem)
{
    int kg = __builtin_amdgcn_readfirstlane(rem >> 9);
    int n  = rem & 511;
    int h  = __builtin_amdgcn_readfirstlane(n >> 6);
    int d  = n & 63;
    const float* wr = Wbig + (size_t)(kg * 8) * HID + h * HD;
    float acc[8] = {0.f, 0.f, 0.f, 0.f, 0.f, 0.f, 0.f, 0.f};
    #pragma unroll 8
    for (int t = 0; t < 64; ++t) {
        float wv = Wsmall[t * 64 + d];      // coalesced across lanes
        #pragma unroll
        for (int j = 0; j < 8; ++j)
            acc[j] = fmaf(wr[(size_t)j * HID + t], wv, acc[j]);  // uniform
    }
    pack_w_store(dst, acc, kg, n);
}

// ---------------------------------------------------------------------------
// ONE launch for all prep+pack work (no internal dependencies):
// [0,576): A packs q,k,v | [576,704): Wv | [704,832): Wo
// [832,960): fold(Wq,Ww) | [960,1088): fold(Wk,Wu) | [1088]: biases + vv2
// ---------------------------------------------------------------------------
__global__ __launch_bounds__(256) void pack_all_kernel(
    const float* __restrict__ q, const float* __restrict__ k, const float* __restrict__ v,
    const float* __restrict__ Wq, const float* __restrict__ bq,
    const float* __restrict__ Wk, const float* __restrict__ bk,
    const float* __restrict__ Wv, const float* __restrict__ Wo,
    const float* __restrict__ Ww, const float* __restrict__ bw,
    const float* __restrict__ Wu, const float* __restrict__ bu,
    const float* __restrict__ vv,
    s8v* __restrict__ Aq, s8v* __restrict__ Ak, s8v* __restrict__ Av,
    s8v* __restrict__ Bq, s8v* __restrict__ Bk, s8v* __restrict__ Bv, s8v* __restrict__ Bo,
    float* __restrict__ bqe, float* __restrict__ bke, float* __restrict__ vv2)
{
    int bx = blockIdx.x, tid = threadIdx.x;
    if (bx < 576) {
        int p = bx / 192;
        int rem = (bx % 192) * 256 + tid;
        const float* src = (p == 0) ? q : (p == 1) ? k : v;
        s8v* dst = (p == 0) ? Aq : (p == 1) ? Ak : Av;
        pack_a_one(src, dst, rem);
    } else if (bx < 704) {
        pack_w_one(Wv, Bv, (bx - 576) * 256 + tid);
    } else if (bx < 832) {
        pack_w_one(Wo, Bo, (bx - 704) * 256 + tid);
    } else if (bx < 960) {
        fold_pack_w_one(Wq, Ww, Bq, (bx - 832) * 256 + tid);
    } else if (bx < 1088) {
        fold_pack_w_one(Wk, Wu, Bk, (bx - 960) * 256 + tid);
    } else {
        for (int i = tid; i < 1088; i += 256) {
            if (i < 512) {
                int h = i >> 6, j = i & 63;
                float s = bw[j];
                for (int t = 0; t < 64; ++t) s = fmaf(bq[h * 64 + t], Ww[t * 64 + j], s);
                bqe[i] = s;
            } else if (i < 1024) {
                int n = i - 512, h = n >> 6, j = n & 63;
                float s = bu[j];
                for (int t = 0; t < 64; ++t) s = fmaf(bk[h * 64 + t], Wu[t * 64 + j], s);
                bke[n] = s;
            } else {
                vv2[i - 1024] = -2.0f * vv[i - 1024];
            }
        }
    }
}

// ---------------------------------------------------------------------------
// MFMA GEMM: FOUR waves per block (256 thr), 32x32 tile (2x2 MFMA 16x16x32),
// K-SPLIT across waves: wave w accumulates base k-tiles 4w..4w+3, then a
// single 16KB LDS exchange + one barrier; each wave reduces and writes one
// acc quadrant.
// 3-term bf16 split per base k-tile: AhBh + AhBl + AlBh (12 MFMA / 8 loads)
// MODE 0: plain  MODE 1: exp2(C1*y)  MODE 2: exp2 + transposed-packed Ek4
// ---------------------------------------------------------------------------
struct Frag { s8v ah0, al0, ah1, al1, bh0, bl0, bh1, bl1; };

__device__ __forceinline__ void load_frag(Frag& f,
    const s8v* __restrict__ a0, const s8v* __restrict__ a1,
    const s8v* __restrict__ b0, const s8v* __restrict__ b1, int kt)
{
    int oh = kt * 64, ol = (16 + kt) * 64;
    f.ah0 = a0[oh]; f.al0 = a0[ol];
    f.ah1 = a1[oh]; f.al1 = a1[ol];
    f.bh0 = b0[oh]; f.bl0 = b0[ol];
    f.bh1 = b1[oh]; f.bl1 = b1[ol];
}

__device__ __forceinline__ void compute_frag(f4v& acc00, f4v& acc01,
                                             f4v& acc10, f4v& acc11, const Frag& f)
{
    acc00 = __builtin_amdgcn_mfma_f32_16x16x32_bf16(f.ah0, f.bh0, acc00, 0, 0, 0);
    acc01 = __builtin_amdgcn_mfma_f32_16x16x32_bf16(f.ah0, f.bh1, acc01, 0, 0, 0);
    acc10 = __builtin_amdgcn_mfma_f32_16x16x32_bf16(f.ah1, f.bh0, acc10, 0, 0, 0);
    acc11 = __builtin_amdgcn_mfma_f32_16x16x32_bf16(f.ah1, f.bh1, acc11, 0, 0, 0);
    acc00 = __builtin_amdgcn_mfma_f32_16x16x32_bf16(f.ah0, f.bl0, acc00, 0, 0, 0);
    acc01 = __builtin_amdgcn_mfma_f32_16x16x32_bf16(f.ah0, f.bl1, acc01, 0, 0, 0);
    acc10 = __builtin_amdgcn_mfma_f32_16x16x32_bf16(f.ah1, f.bl0, acc10, 0, 0, 0);
    acc11 = __builtin_amdgcn_mfma_f32_16x16x32_bf16(f.ah1, f.bl1, acc11, 0, 0, 0);
    acc00 = __builtin_amdgcn_mfma_f32_16x16x32_bf16(f.al0, f.bh0, acc00, 0, 0, 0);
    acc01 = __builtin_amdgcn_mfma_f32_16x16x32_bf16(f.al0, f.bh1, acc01, 0, 0, 0);
    acc10 = __builtin_amdgcn_mfma_f32_16x16x32_bf16(f.al1, f.bh0, acc10, 0, 0, 0);
    acc11 = __builtin_amdgcn_mfma_f32_16x16x32_bf16(f.al1, f.bh1, acc11, 0, 0, 0);
}

template <int MODE>
__device__ __forceinline__ void mfma_gemm_body(
    const s8v* __restrict__ Ap, const s8v* __restrict__ Bp,
    const float* __restrict__ bias, float* __restrict__ out,
    int mt0, int nt0)
{
    __shared__ f4v red[4][4][64];   // [src wave][acc quadrant][lane] = 16 KB

    int tid  = threadIdx.x;
    int wave = __builtin_amdgcn_readfirstlane(tid >> 6);
    int lane = tid & 63;

    const s8v* a0p = Ap + (size_t)(mt0 * 32) * 64 + lane;
    const s8v* a1p = a0p + (size_t)32 * 64;
    const s8v* b0p = Bp + (size_t)(nt0 * 32) * 64 + lane;
    const s8v* b1p = b0p + (size_t)32 * 64;

    f4v acc00 = {0.f, 0.f, 0.f, 0.f};
    f4v acc01 = {0.f, 0.f, 0.f, 0.f};
    f4v acc10 = {0.f, 0.f, 0.f, 0.f};
    f4v acc11 = {0.f, 0.f, 0.f, 0.f};

    // wave w owns base k-tiles 4w .. 4w+3 (each with hi+lo sections)
    int kt0 = wave * 4;
    Frag X, Y;
    load_frag(X, a0p, a1p, b0p, b1p, kt0);
    load_frag(Y, a0p, a1p, b0p, b1p, kt0 + 1);
    compute_frag(acc00, acc01, acc10, acc11, X);
    load_frag(X, a0p, a1p, b0p, b1p, kt0 + 2);
    compute_frag(acc00, acc01, acc10, acc11, Y);
    load_frag(Y, a0p, a1p, b0p, b1p, kt0 + 3);
    compute_frag(acc00, acc01, acc10, acc11, X);
    compute_frag(acc00, acc01, acc10, acc11, Y);

    red[wave][0][lane] = acc00;
    red[wave][1][lane] = acc01;
    red[wave][2][lane] = acc10;
    red[wave][3][lane] = acc11;
    __syncthreads();

    // wave w reduces + writes acc quadrant w:
    // 0 -> (row0,col0)  1 -> (row0,col1)  2 -> (row1,col0)  3 -> (row1,col1)
    f4v s = red[0][wave][lane] + red[1][wave][lane]
          + red[2][wave][lane] + red[3][wave][lane];

    // C/D layout: row = quad*4 + reg, col = lane&15.
    int quad = lane >> 4, c16 = lane & 15;
    int R0 = mt0 * 16 + quad * 4 + (wave >> 1) * 16;
    int C  = nt0 * 16 + c16 + (wave & 1) * 16;
    float biasC = bias[C];

    #pragma unroll
    for (int r = 0; r < 4; ++r) {
        float yy = s[r] + biasC;
        if (MODE != 0) yy = __builtin_amdgcn_exp2f(C1 * yy);
        if (MODE == 2) {
            int ROW = R0 + r;
            int b2 = ROW / SEQ, kk = ROW - b2 * SEQ;
            int hh = C >> 6, dd = C & 63;
            out[(((size_t)((b2 * 8 + hh) * 16 + (dd >> 2)) * SEQ + kk) << 2)
                + (dd & 3)] = yy;
        } else {
            out[(size_t)(R0 + r) * HID + C] = yy;
        }
    }
}

__global__ __launch_bounds__(256) void proj3_mfma_kernel(
    const s8v* __restrict__ Aq, const s8v* __restrict__ Ak, const s8v* __restrict__ Av,
    const s8v* __restrict__ Bq, const s8v* __restrict__ Bk, const s8v* __restrict__ Bv,
    const float* __restrict__ bqe, const float* __restrict__ bke, const float* __restrict__ bv,
    float* __restrict__ Eq, float* __restrict__ Ek4, float* __restrict__ V)
{
    int p = blockIdx.z;
    int mt0 = blockIdx.x * 2, nt0 = blockIdx.y * 2;
    if (p == 0)      mfma_gemm_body<1>(Aq, Bq, bqe, Eq,  mt0, nt0);
    else if (p == 1) mfma_gemm_body<2>(Ak, Bk, bke, Ek4, mt0, nt0);
    else             mfma_gemm_body<0>(Av, Bv, bv,  V,   mt0, nt0);
}

__global__ __launch_bounds__(256) void out_mfma_kernel(
    const s8v* __restrict__ Ax, const s8v* __restrict__ Bo,
    const float* __restrict__ bo, float* __restrict__ out)
{
    mfma_gemm_body<0>(Ax, Bo, bo, out, blockIdx.x * 2, blockIdx.y * 2);
}

// ---------------------------------------------------------------------------
// attention (R13: R11 streaming structure, 4 q-rows per wave):
// 128-thread blocks (2 waves), 768 blocks = 3 blocks/CU uniform, no barriers.
// Each wave owns 4 q-rows -> Ek/V L2 traffic halves vs R11 (604 -> 302 MB)
// while keeping the per-wave software-prefetch streams that hide L2 latency.
// XCD swizzle: xcd = blk & 7; each XCD handles exactly 2 bh slices.
// Rotation: wave w starts at d-chunk 2w -> decorrelated Ek address streams.
// Eq/vv2 wave-uniform -> scalar; Ek4 coalesced b128, per-kt prefetch.
// Epilogue packs X directly into Ax (bf16 2-section MFMA swizzle).
// ---------------------------------------------------------------------------
__device__ __forceinline__ void pack_pair_to_Ax(s8v* __restrict__ Ax,
    float4 xa, float4 xb, int rowbase, int h, int lane)
{
    // lanes 0..15 active: xa/xb hold rows rowbase/rowbase+1 (float4 at d4=lane)
    float4 pa, pb;
    pa.x = __shfl_xor(xa.x, 1); pa.y = __shfl_xor(xa.y, 1);
    pa.z = __shfl_xor(xa.z, 1); pa.w = __shfl_xor(xa.w, 1);
    pb.x = __shfl_xor(xb.x, 1); pb.y = __shfl_xor(xb.y, 1);
    pb.z = __shfl_xor(xb.z, 1); pb.w = __shfl_xor(xb.w, 1);
    float vals[8];
    int row;
    if ((lane & 1) == 0) {
        vals[0] = xa.x; vals[1] = xa.y; vals[2] = xa.z; vals[3] = xa.w;
        vals[4] = pa.x; vals[5] = pa.y; vals[6] = pa.z; vals[7] = pa.w;
        row = rowbase;
    } else {
        vals[0] = pb.x; vals[1] = pb.y; vals[2] = pb.z; vals[3] = pb.w;
        vals[4] = xb.x; vals[5] = xb.y; vals[6] = xb.z; vals[7] = xb.w;
        row = rowbase + 1;
    }
    int g = h * 8 + (lane >> 1);   // global 8-col group
    s8v hi, lo;
    #pragma unroll
    for (int j = 0; j < 8; ++j) {
        unsigned short hh = bf16_rne(vals[j]);
        hi[j] = (short)hh;
        lo[j] = (short)bf16_rne(vals[j] - bf16_val(hh));
    }
    int mt = row >> 4, kt2 = g >> 2;
    int lanei = (row & 15) | ((g & 3) << 4);
    size_t base = ((size_t)mt * 32) * 64 + lanei;
    Ax[base + (size_t)kt2 * 64]        = hi;
    Ax[base + (size_t)(16 + kt2) * 64] = lo;
}

__global__ __launch_bounds__(128, 2) void attn_kernel(
    const float* __restrict__ Eq, const float* __restrict__ Ek4,
    const float* __restrict__ V, const float* __restrict__ vv2,
    float* __restrict__ attnOut, s8v* __restrict__ Ax)
{
    __shared__ float4 aP[2][SEQ];   // 12 KB: (a0,a1,a2,a3) per k, per wave

    int blk = blockIdx.x;
    int xcd = blk & 7, slot = blk >> 3;       // slot in [0,96)
    int part = slot / 48, qblk = slot % 48;
    int bh = xcd * 2 + part;
    int b = bh >> 3, h = bh & 7;
    int tid = threadIdx.x;
    int wave = __builtin_amdgcn_readfirstlane(tid >> 6);
    int lane = tid & 63;
    int q0 = qblk * 8 + wave * 4;             // rows q0 .. q0+3

    const float* eqb = Eq + (size_t)(b * SEQ + q0) * HID + h * HD;  // uniform
    const float4* ekbase = (const float4*)Ek4 + (size_t)bh * 16 * SEQ + lane;

    float e0[6], e1[6], e2[6], e3[6];
    #pragma unroll
    for (int t = 0; t < 6; ++t) { e0[t] = 0.f; e1[t] = 0.f; e2[t] = 0.f; e3[t] = 0.f; }

    #pragma unroll 1
    for (int cc = 0; cc < 4; ++cc) {
        int c = (cc + wave * 2) & 3;      // wave-rotated chunk order (uniform)
        float g0[16], g1[16], g2[16], g3[16], w[16];
        #pragma unroll
        for (int j = 0; j < 16; ++j) {
            g0[j] = eqb[c * 16 + j];              // wave-uniform -> s_load
            g1[j] = eqb[HID + c * 16 + j];
            g2[j] = eqb[2 * HID + c * 16 + j];
            g3[j] = eqb[3 * HID + c * 16 + j];
            w[j]  = vv2[c * 16 + j];
        }
        const float4* ekc = ekbase + (size_t)c * 4 * SEQ;
        float4 k0 = ekc[0 * SEQ], k1 = ekc[1 * SEQ];
        float4 k2 = ekc[2 * SEQ], k3 = ekc[3 * SEQ];
        #pragma unroll
        for (int kt = 0; kt < 6; ++kt) {
            float4 n0, n1, n2, n3;
            if (kt < 5) {
                const float4* np = ekc + (kt + 1) * 64;
                n0 = np[0 * SEQ]; n1 = np[1 * SEQ];
                n2 = np[2 * SEQ]; n3 = np[3 * SEQ];
            }
            float r0 = e0[kt], r1 = e1[kt], r2 = e2[kt], r3 = e3[kt];
            #define EN(J, KV)                                                      \
            {                                                                      \
                float t0 = __builtin_amdgcn_rcpf(fmaf(g0[J], (KV), 1.f));          \
                float t1 = __builtin_amdgcn_rcpf(fmaf(g1[J], (KV), 1.f));          \
                float t2 = __builtin_amdgcn_rcpf(fmaf(g2[J], (KV), 1.f));          \
                float t3 = __builtin_amdgcn_rcpf(fmaf(g3[J], (KV), 1.f));          \
                r0 = fmaf(w[J], t0, r0);                                           \
                r1 = fmaf(w[J], t1, r1);                                           \
                r2 = fmaf(w[J], t2, r2);                                           \
                r3 = fmaf(w[J], t3, r3);                                           \
            }
            EN(0,  k0.x) EN(1,  k0.y) EN(2,  k0.z) EN(3,  k0.w)
            EN(4,  k1.x) EN(5,  k1.y) EN(6,  k1.z) EN(7,  k1.w)
            EN(8,  k2.x) EN(9,  k2.y) EN(10, k2.z) EN(11, k2.w)
            EN(12, k3.x) EN(13, k3.y) EN(14, k3.z) EN(15, k3.w)
            #undef EN
            e0[kt] = r0; e1[kt] = r1; e2[kt] = r2; e3[kt] = r3;
            k0 = n0; k1 = n1; k2 = n2; k3 = n3;
        }
    }

    // Prefetch first 8 V vectors for the attn@V phase (independent of softmax)
    int ko = lane >> 4, d4p = lane & 15;
    const float4* vb = (const float4*)&V[(size_t)b * SEQ * HID + h * HD + d4p * 4];
    float4 vpre[8];
    #pragma unroll
    for (int i = 0; i < 8; ++i)
        vpre[i] = vb[(size_t)(ko + i * 4) * (HID / 4)];

    // softmax over k (384 = 6 tiles x 64 lanes), 4 rows
    float m0 = e0[0], m1 = e1[0], m2 = e2[0], m3 = e3[0];
    #pragma unroll
    for (int t = 1; t < 6; ++t) {
        m0 = fmaxf(m0, e0[t]); m1 = fmaxf(m1, e1[t]);
        m2 = fmaxf(m2, e2[t]); m3 = fmaxf(m3, e3[t]);
    }
    #pragma unroll
    for (int off = 1; off < 64; off <<= 1) {
        m0 = fmaxf(m0, __shfl_xor(m0, off));
        m1 = fmaxf(m1, __shfl_xor(m1, off));
        m2 = fmaxf(m2, __shfl_xor(m2, off));
        m3 = fmaxf(m3, __shfl_xor(m3, off));
    }
    float a0[6], a1[6], a2[6], a3[6];
    float s0 = 0.f, s1 = 0.f, s2 = 0.f, s3 = 0.f;
    #pragma unroll
    for (int t = 0; t < 6; ++t) {
        a0[t] = __builtin_amdgcn_exp2f((e0[t] - m0) * SSCL); s0 += a0[t];
        a1[t] = __builtin_amdgcn_exp2f((e1[t] - m1) * SSCL); s1 += a1[t];
        a2[t] = __builtin_amdgcn_exp2f((e2[t] - m2) * SSCL); s2 += a2[t];
        a3[t] = __builtin_amdgcn_exp2f((e3[t] - m3) * SSCL); s3 += a3[t];
    }
    #pragma unroll
    for (int off = 1; off < 64; off <<= 1) {
        s0 += __shfl_xor(s0, off);
        s1 += __shfl_xor(s1, off);
        s2 += __shfl_xor(s2, off);
        s3 += __shfl_xor(s3, off);
    }
    float z0 = __builtin_amdgcn_rcpf(s0), z1 = __builtin_amdgcn_rcpf(s1);
    float z2 = __builtin_amdgcn_rcpf(s2), z3 = __builtin_amdgcn_rcpf(s3);

    size_t abase = (size_t)bh * SEQ * SEQ + (size_t)q0 * SEQ;
    #pragma unroll
    for (int t = 0; t < 6; ++t) {
        float v0 = a0[t] * z0, v1 = a1[t] * z1;
        float v2 = a2[t] * z2, v3 = a3[t] * z3;
        attnOut[abase + 0 * SEQ + t * 64 + lane] = v0;
        attnOut[abase + 1 * SEQ + t * 64 + lane] = v1;
        attnOut[abase + 2 * SEQ + t * 64 + lane] = v2;
        attnOut[abase + 3 * SEQ + t * 64 + lane] = v3;
        aP[wave][t * 64 + lane] = make_float4(v0, v1, v2, v3);
    }
    // no barrier: aP[wave] written and read by the same wave

    // attn @ V: lane = ko*16 + d4p; 4 k-phases, float4 over d, 4 q rows.
    // First 8 iterations use the prefetched vectors.
    float4 x0 = make_float4(0.f, 0.f, 0.f, 0.f);
    float4 x1 = make_float4(0.f, 0.f, 0.f, 0.f);
    float4 x2 = make_float4(0.f, 0.f, 0.f, 0.f);
    float4 x3 = make_float4(0.f, 0.f, 0.f, 0.f);
    #pragma unroll
    for (int i = 0; i < 8; ++i) {
        int k = ko + i * 4;
        float4 v = vpre[i];
        float4 a = aP[wave][k];
        x0.x = fmaf(a.x, v.x, x0.x); x0.y = fmaf(a.x, v.y, x0.y);
        x0.z = fmaf(a.x, v.z, x0.z); x0.w = fmaf(a.x, v.w, x0.w);
        x1.x = fmaf(a.y, v.x, x1.x); x1.y = fmaf(a.y, v.y, x1.y);
        x1.z = fmaf(a.y, v.z, x1.z); x1.w = fmaf(a.y, v.w, x1.w);
        x2.x = fmaf(a.z, v.x, x2.x); x2.y = fmaf(a.z, v.y, x2.y);
        x2.z = fmaf(a.z, v.z, x2.z); x2.w = fmaf(a.z, v.w, x2.w);
        x3.x = fmaf(a.w, v.x, x3.x); x3.y = fmaf(a.w, v.y, x3.y);
        x3.z = fmaf(a.w, v.z, x3.z); x3.w = fmaf(a.w, v.w, x3.w);
    }
    #pragma unroll 4
    for (int k = ko + 32; k < SEQ; k += 4) {
        float4 v = vb[(size_t)k * (HID / 4)];
        float4 a = aP[wave][k];
        x0.x = fmaf(a.x, v.x, x0.x); x0.y = fmaf(a.x, v.y, x0.y);
        x0.z = fmaf(a.x, v.z, x0.z); x0.w = fmaf(a.x, v.w, x0.w);
        x1.x = fmaf(a.y, v.x, x1.x); x1.y = fmaf(a.y, v.y, x1.y);
        x1.z = fmaf(a.y, v.z, x1.z); x1.w = fmaf(a.y, v.w, x1.w);
        x2.x = fmaf(a.z, v.x, x2.x); x2.y = fmaf(a.z, v.y, x2.y);
        x2.z = fmaf(a.z, v.z, x2.z); x2.w = fmaf(a.z, v.w, x2.w);
        x3.x = fmaf(a.w, v.x, x3.x); x3.y = fmaf(a.w, v.y, x3.y);
        x3.z = fmaf(a.w, v.z, x3.z); x3.w = fmaf(a.w, v.w, x3.w);
    }
    #pragma unroll
    for (int off = 16; off < 64; off <<= 1) {
        x0.x += __shfl_xor(x0.x, off); x0.y += __shfl_xor(x0.y, off);
        x0.z += __shfl_xor(x0.z, off); x0.w += __shfl_xor(x0.w, off);
        x1.x += __shfl_xor(x1.x, off); x1.y += __shfl_xor(x1.y, off);
        x1.z += __shfl_xor(x1.z, off); x1.w += __shfl_xor(x1.w, off);
        x2.x += __shfl_xor(x2.x, off); x2.y += __shfl_xor(x2.y, off);
        x2.z += __shfl_xor(x2.z, off); x2.w += __shfl_xor(x2.w, off);
        x3.x += __shfl_xor(x3.x, off); x3.y += __shfl_xor(x3.y, off);
        x3.z += __shfl_xor(x3.z, off); x3.w += __shfl_xor(x3.w, off);
    }

    // Pack X rows q0..q0+3 (this head's 64 cols) straight into Ax.
    if (ko == 0) {
        pack_pair_to_Ax(Ax, x0, x1, b * SEQ + q0,     h, lane);
        pack_pair_to_Ax(Ax, x2, x3, b * SEQ + q0 + 2, h, lane);
    }
}

// ---------------------------------------------------------------------------
extern "C" void kernel_launch(void* const* d_in, const int* in_sizes, int n_in,
                              void* d_out, int out_size, void* d_ws, size_t ws_size,
                              hipStream_t stream)
{
    const float* query = (const float*)d_in[0];
    const float* key   = (const float*)d_in[1];
    const float* value = (const float*)d_in[2];
    const float* Wq = (const float*)d_in[3];
    const float* bq = (const float*)d_in[4];
    const float* Wk = (const float*)d_in[5];
    const float* bk = (const float*)d_in[6];
    const float* Wv = (const float*)d_in[7];
    const float* bv = (const float*)d_in[8];
    const float* Ww = (const float*)d_in[9];
    const float* bw = (const float*)d_in[10];
    const float* Wu = (const float*)d_in[11];
    const float* bu = (const float*)d_in[12];
    const float* vv = (const float*)d_in[13];
    const float* Wo = (const float*)d_in[14];
    const float* bo = (const float*)d_in[15];

    float* out_x    = (float*)d_out;                 // [2,384,512]
    float* out_attn = out_x + (size_t)MROWS * HID;   // [2,8,384,384]

    float* ws  = (float*)d_ws;
    float* bqe = ws;                 // 512
    float* bke = bqe + 512;          // 512
    float* vv2 = bke + 512;          // 64
    float* EqB = vv2 + 64;           // 393216
    float* Ek4 = EqB + 393216;       // 393216 (transposed-packed)
    float* Vw  = Ek4 + 393216;       // 393216

    s8v* packs = (s8v*)(Vw + 393216);        // 16B-aligned
    s8v* Aq = packs;                          // APACK_S8 each
    s8v* Ak = Aq + APACK_S8;
    s8v* Av = Ak + APACK_S8;
    s8v* Ax = Av + APACK_S8;
    s8v* Bq = Ax + APACK_S8;                  // BPACK_S8 each
    s8v* Bk = Bq + BPACK_S8;
    s8v* Bv = Bk + BPACK_S8;
    s8v* Bo = Bv + BPACK_S8;

    pack_all_kernel<<<dim3(1089), 256, 0, stream>>>(
        query, key, value,
        Wq, bq, Wk, bk, Wv, Wo, Ww, bw, Wu, bu, vv,
        Aq, Ak, Av, Bq, Bk, Bv, Bo,
        bqe, bke, vv2);
    proj3_mfma_kernel<<<dim3(24, 16, 3), 256, 0, stream>>>(Aq, Ak, Av, Bq, Bk, Bv,
                                                           bqe, bke, bv,
                                                           EqB, Ek4, Vw);
    attn_kernel<<<dim3(768), 128, 0, stream>>>(EqB, Ek4, Vw, vv2, out_attn, Ax);
    out_mfma_kernel<<<dim3(24, 16), 256, 0, stream>>>(Ax, Bo, bo, out_x);
}

// Round 4
// 142.480 us; speedup vs baseline: 1.1740x; 1.0236x over previous
//
#include <hip/hip_runtime.h>

#define HID 512
#define HEADS 8
#define HD 64
#define BATCH 2
#define SEQ 384
#define MROWS (BATCH * SEQ)  // 768
// 2-section packs: [Ah | Al] and [Bh | Bl], 16 base k-tiles each (K=512)
#define APACK_S8 (48 * 32 * 64)   // 98304 s8-chunks per packed A
#define BPACK_S8 (32 * 32 * 64)   // 65536 s8-chunks per packed B

// 2*log2(e): Eq = exp2(C1 * qW) == exp(2*qW)
#define C1 2.8853900817779268f
// log2(e)/8: softmax exponent scale (energy = raw/8)
#define SSCL 0.18033688011112043f

typedef __attribute__((ext_vector_type(8))) short s8v;   // 8 bf16 (4 VGPR)
typedef __attribute__((ext_vector_type(4))) float f4v;   // MFMA acc

__device__ __forceinline__ unsigned short bf16_rne(float x) {
    union { float f; unsigned u; } v; v.f = x;
    unsigned r = v.u + 0x7FFFu + ((v.u >> 16) & 1u);
    return (unsigned short)(r >> 16);
}
__device__ __forceinline__ float bf16_val(unsigned short h) {
    union { float f; unsigned u; } v; v.u = ((unsigned)h) << 16; return v.f;
}

// ---------------------------------------------------------------------------
// Pack A [768x512 f32] -> [Ah | Al] bf16 in MFMA swizzle:
// s8 index (mt*32 + sec*16 + kt)*64 + lane, lane = (m&15) | ((g&3)<<4)
// ---------------------------------------------------------------------------
__device__ __forceinline__ void pack_a_one(const float* __restrict__ src,
                                           s8v* __restrict__ dst, int rem)
{
    int g = rem & 63, m = rem >> 6;           // c = 8g .. 8g+7
    const float4* sp = (const float4*)(src + (size_t)m * HID + g * 8);
    float4 v0 = sp[0], v1 = sp[1];
    float vals[8] = {v0.x, v0.y, v0.z, v0.w, v1.x, v1.y, v1.z, v1.w};
    s8v hi, lo;
    #pragma unroll
    for (int j = 0; j < 8; ++j) {
        unsigned short h = bf16_rne(vals[j]);
        hi[j] = (short)h;
        lo[j] = (short)bf16_rne(vals[j] - bf16_val(h));
    }
    int mt = m >> 4, kt = g >> 2;
    int lanei = (m & 15) | ((g & 3) << 4);
    size_t base = ((size_t)mt * 32) * 64 + lanei;
    dst[base + (size_t)kt * 64]        = hi;  // sec0: Ah
    dst[base + (size_t)(16 + kt) * 64] = lo;  // sec1: Al
}

// ---------------------------------------------------------------------------
// Pack W [512x512 f32, (k,n)] -> [Bh | Bl] in MFMA swizzle
// ---------------------------------------------------------------------------
__device__ __forceinline__ void pack_w_store(s8v* __restrict__ dst,
                                             const float vals[8], int kg, int n)
{
    s8v hi, lo;
    #pragma unroll
    for (int j = 0; j < 8; ++j) {
        unsigned short h = bf16_rne(vals[j]);
        hi[j] = (short)h;
        lo[j] = (short)bf16_rne(vals[j] - bf16_val(h));
    }
    int nt = n >> 4, kt = kg >> 2;
    int lanei = (n & 15) | ((kg & 3) << 4);
    size_t base = ((size_t)nt * 32) * 64 + lanei;
    dst[base + (size_t)kt * 64]        = hi;  // sec0: Bh
    dst[base + (size_t)(16 + kt) * 64] = lo;  // sec1: Bl
}

__device__ __forceinline__ void pack_w_one(const float* __restrict__ W,
                                           s8v* __restrict__ dst, int rem)
{
    int kg = rem >> 9, n = rem & 511;         // k = 8kg .. 8kg+7
    float vals[8];
    #pragma unroll
    for (int j = 0; j < 8; ++j)
        vals[j] = W[(size_t)(kg * 8 + j) * HID + n];   // coalesced across n
    pack_w_store(dst, vals, kg, n);
}

// fold Wbig(512x512) @ blockdiag(Wsmall 64x64) on the fly, then pack
__device__ __forceinline__ void fold_pack_w_one(const float* __restrict__ Wbig,
                                                const float* __restrict__ Wsmall,
                                                s8v* __restrict__ dst, int rem)
{
    int kg = __builtin_amdgcn_readfirstlane(rem >> 9);
    int n  = rem & 511;
    int h  = __builtin_amdgcn_readfirstlane(n >> 6);
    int d  = n & 63;
    const float* wr = Wbig + (size_t)(kg * 8) * HID + h * HD;
    float acc[8] = {0.f, 0.f, 0.f, 0.f, 0.f, 0.f, 0.f, 0.f};
    #pragma unroll 8
    for (int t = 0; t < 64; ++t) {
        float wv = Wsmall[t * 64 + d];      // coalesced across lanes
        #pragma unroll
        for (int j = 0; j < 8; ++j)
            acc[j] = fmaf(wr[(size_t)j * HID + t], wv, acc[j]);  // uniform
    }
    pack_w_store(dst, acc, kg, n);
}

// ---------------------------------------------------------------------------
// ONE launch for all prep+pack work (no internal dependencies):
// [0,576): A packs q,k,v | [576,704): Wv | [704,832): Wo
// [832,960): fold(Wq,Ww) | [960,1088): fold(Wk,Wu) | [1088]: biases + vv2
// ---------------------------------------------------------------------------
__global__ __launch_bounds__(256) void pack_all_kernel(
    const float* __restrict__ q, const float* __restrict__ k, const float* __restrict__ v,
    const float* __restrict__ Wq, const float* __restrict__ bq,
    const float* __restrict__ Wk, const float* __restrict__ bk,
    const float* __restrict__ Wv, const float* __restrict__ Wo,
    const float* __restrict__ Ww, const float* __restrict__ bw,
    const float* __restrict__ Wu, const float* __restrict__ bu,
    const float* __restrict__ vv,
    s8v* __restrict__ Aq, s8v* __restrict__ Ak, s8v* __restrict__ Av,
    s8v* __restrict__ Bq, s8v* __restrict__ Bk, s8v* __restrict__ Bv, s8v* __restrict__ Bo,
    float* __restrict__ bqe, float* __restrict__ bke, float* __restrict__ vv2)
{
    int bx = blockIdx.x, tid = threadIdx.x;
    if (bx < 576) {
        int p = bx / 192;
        int rem = (bx % 192) * 256 + tid;
        const float* src = (p == 0) ? q : (p == 1) ? k : v;
        s8v* dst = (p == 0) ? Aq : (p == 1) ? Ak : Av;
        pack_a_one(src, dst, rem);
    } else if (bx < 704) {
        pack_w_one(Wv, Bv, (bx - 576) * 256 + tid);
    } else if (bx < 832) {
        pack_w_one(Wo, Bo, (bx - 704) * 256 + tid);
    } else if (bx < 960) {
        fold_pack_w_one(Wq, Ww, Bq, (bx - 832) * 256 + tid);
    } else if (bx < 1088) {
        fold_pack_w_one(Wk, Wu, Bk, (bx - 960) * 256 + tid);
    } else {
        for (int i = tid; i < 1088; i += 256) {
            if (i < 512) {
                int h = i >> 6, j = i & 63;
                float s = bw[j];
                for (int t = 0; t < 64; ++t) s = fmaf(bq[h * 64 + t], Ww[t * 64 + j], s);
                bqe[i] = s;
            } else if (i < 1024) {
                int n = i - 512, h = n >> 6, j = n & 63;
                float s = bu[j];
                for (int t = 0; t < 64; ++t) s = fmaf(bk[h * 64 + t], Wu[t * 64 + j], s);
                bke[n] = s;
            } else {
                vv2[i - 1024] = -2.0f * vv[i - 1024];
            }
        }
    }
}

// ---------------------------------------------------------------------------
// MFMA GEMM: FOUR waves per block (256 thr), 32x32 tile (2x2 MFMA 16x16x32),
// K-SPLIT across waves: wave w accumulates base k-tiles 4w..4w+3, then a
// single 16KB LDS exchange + one barrier; each wave reduces and writes one
// acc quadrant.
// 3-term bf16 split per base k-tile: AhBh + AhBl + AlBh (12 MFMA / 8 loads)
// MODE 0: plain  MODE 1: exp2(C1*y)  MODE 2: exp2 + transposed-packed Ek4
// ---------------------------------------------------------------------------
struct Frag { s8v ah0, al0, ah1, al1, bh0, bl0, bh1, bl1; };

__device__ __forceinline__ void load_frag(Frag& f,
    const s8v* __restrict__ a0, const s8v* __restrict__ a1,
    const s8v* __restrict__ b0, const s8v* __restrict__ b1, int kt)
{
    int oh = kt * 64, ol = (16 + kt) * 64;
    f.ah0 = a0[oh]; f.al0 = a0[ol];
    f.ah1 = a1[oh]; f.al1 = a1[ol];
    f.bh0 = b0[oh]; f.bl0 = b0[ol];
    f.bh1 = b1[oh]; f.bl1 = b1[ol];
}

__device__ __forceinline__ void compute_frag(f4v& acc00, f4v& acc01,
                                             f4v& acc10, f4v& acc11, const Frag& f)
{
    acc00 = __builtin_amdgcn_mfma_f32_16x16x32_bf16(f.ah0, f.bh0, acc00, 0, 0, 0);
    acc01 = __builtin_amdgcn_mfma_f32_16x16x32_bf16(f.ah0, f.bh1, acc01, 0, 0, 0);
    acc10 = __builtin_amdgcn_mfma_f32_16x16x32_bf16(f.ah1, f.bh0, acc10, 0, 0, 0);
    acc11 = __builtin_amdgcn_mfma_f32_16x16x32_bf16(f.ah1, f.bh1, acc11, 0, 0, 0);
    acc00 = __builtin_amdgcn_mfma_f32_16x16x32_bf16(f.ah0, f.bl0, acc00, 0, 0, 0);
    acc01 = __builtin_amdgcn_mfma_f32_16x16x32_bf16(f.ah0, f.bl1, acc01, 0, 0, 0);
    acc10 = __builtin_amdgcn_mfma_f32_16x16x32_bf16(f.ah1, f.bl0, acc10, 0, 0, 0);
    acc11 = __builtin_amdgcn_mfma_f32_16x16x32_bf16(f.ah1, f.bl1, acc11, 0, 0, 0);
    acc00 = __builtin_amdgcn_mfma_f32_16x16x32_bf16(f.al0, f.bh0, acc00, 0, 0, 0);
    acc01 = __builtin_amdgcn_mfma_f32_16x16x32_bf16(f.al0, f.bh1, acc01, 0, 0, 0);
    acc10 = __builtin_amdgcn_mfma_f32_16x16x32_bf16(f.al1, f.bh0, acc10, 0, 0, 0);
    acc11 = __builtin_amdgcn_mfma_f32_16x16x32_bf16(f.al1, f.bh1, acc11, 0, 0, 0);
}

template <int MODE>
__device__ __forceinline__ void mfma_gemm_body(
    const s8v* __restrict__ Ap, const s8v* __restrict__ Bp,
    const float* __restrict__ bias, float* __restrict__ out,
    int mt0, int nt0)
{
    __shared__ f4v red[4][4][64];   // [src wave][acc quadrant][lane] = 16 KB

    int tid  = threadIdx.x;
    int wave = __builtin_amdgcn_readfirstlane(tid >> 6);
    int lane = tid & 63;

    const s8v* a0p = Ap + (size_t)(mt0 * 32) * 64 + lane;
    const s8v* a1p = a0p + (size_t)32 * 64;
    const s8v* b0p = Bp + (size_t)(nt0 * 32) * 64 + lane;
    const s8v* b1p = b0p + (size_t)32 * 64;

    f4v acc00 = {0.f, 0.f, 0.f, 0.f};
    f4v acc01 = {0.f, 0.f, 0.f, 0.f};
    f4v acc10 = {0.f, 0.f, 0.f, 0.f};
    f4v acc11 = {0.f, 0.f, 0.f, 0.f};

    // wave w owns base k-tiles 4w .. 4w+3 (each with hi+lo sections)
    int kt0 = wave * 4;
    Frag X, Y;
    load_frag(X, a0p, a1p, b0p, b1p, kt0);
    load_frag(Y, a0p, a1p, b0p, b1p, kt0 + 1);
    compute_frag(acc00, acc01, acc10, acc11, X);
    load_frag(X, a0p, a1p, b0p, b1p, kt0 + 2);
    compute_frag(acc00, acc01, acc10, acc11, Y);
    load_frag(Y, a0p, a1p, b0p, b1p, kt0 + 3);
    compute_frag(acc00, acc01, acc10, acc11, X);
    compute_frag(acc00, acc01, acc10, acc11, Y);

    red[wave][0][lane] = acc00;
    red[wave][1][lane] = acc01;
    red[wave][2][lane] = acc10;
    red[wave][3][lane] = acc11;
    __syncthreads();

    // wave w reduces + writes acc quadrant w:
    // 0 -> (row0,col0)  1 -> (row0,col1)  2 -> (row1,col0)  3 -> (row1,col1)
    f4v s = red[0][wave][lane] + red[1][wave][lane]
          + red[2][wave][lane] + red[3][wave][lane];

    // C/D layout: row = quad*4 + reg, col = lane&15.
    int quad = lane >> 4, c16 = lane & 15;
    int R0 = mt0 * 16 + quad * 4 + (wave >> 1) * 16;
    int C  = nt0 * 16 + c16 + (wave & 1) * 16;
    float biasC = bias[C];

    #pragma unroll
    for (int r = 0; r < 4; ++r) {
        float yy = s[r] + biasC;
        if (MODE != 0) yy = __builtin_amdgcn_exp2f(C1 * yy);
        if (MODE == 2) {
            int ROW = R0 + r;
            int b2 = ROW / SEQ, kk = ROW - b2 * SEQ;
            int hh = C >> 6, dd = C & 63;
            out[(((size_t)((b2 * 8 + hh) * 16 + (dd >> 2)) * SEQ + kk) << 2)
                + (dd & 3)] = yy;
        } else {
            out[(size_t)(R0 + r) * HID + C] = yy;
        }
    }
}

__global__ __launch_bounds__(256) void proj3_mfma_kernel(
    const s8v* __restrict__ Aq, const s8v* __restrict__ Ak, const s8v* __restrict__ Av,
    const s8v* __restrict__ Bq, const s8v* __restrict__ Bk, const s8v* __restrict__ Bv,
    const float* __restrict__ bqe, const float* __restrict__ bke, const float* __restrict__ bv,
    float* __restrict__ Eq, float* __restrict__ Ek4, float* __restrict__ V)
{
    int p = blockIdx.z;
    int mt0 = blockIdx.x * 2, nt0 = blockIdx.y * 2;
    if (p == 0)      mfma_gemm_body<1>(Aq, Bq, bqe, Eq,  mt0, nt0);
    else if (p == 1) mfma_gemm_body<2>(Ak, Bk, bke, Ek4, mt0, nt0);
    else             mfma_gemm_body<0>(Av, Bv, bv,  V,   mt0, nt0);
}

__global__ __launch_bounds__(256) void out_mfma_kernel(
    const s8v* __restrict__ Ax, const s8v* __restrict__ Bo,
    const float* __restrict__ bo, float* __restrict__ out)
{
    mfma_gemm_body<0>(Ax, Bo, bo, out, blockIdx.x * 2, blockIdx.y * 2);
}

// ---------------------------------------------------------------------------
// attention (R14: d-split energy / k-split PV across waves, LDS partials):
// 1536 blocks x 256 thr; block = 4 q-rows of one bh. Energy: wave w streams
// ONLY d-chunk w of Ek (24.5 KB, one long independent prefetched stream, no
// barriers) for all 4 rows -> partial energies to LDS -> 1 barrier -> wave w
// finishes row w (sum partials + softmax + attnOut + aP). PV: wave w covers
// k in [96w,96w+96) reading 24.5 KB of V; float4 partials summed via LDS.
// Total Ek+V L2 traffic 300 MB (R11: 604) at 3 waves/SIMD resident.
// XCD swizzle: xcd = blk & 7; each XCD owns exactly 2 bh slices.
// ---------------------------------------------------------------------------
__global__ __launch_bounds__(256, 3) void attn_kernel(
    const float* __restrict__ Eq, const float* __restrict__ Ek4,
    const float* __restrict__ V, const float* __restrict__ vv2,
    float* __restrict__ attnOut, s8v* __restrict__ Ax)
{
    __shared__ __align__(16) float epart[4][4][SEQ];  // 24 KB [src wave][row][k]; aliased by xpart in PV
    __shared__ float aP[4][SEQ];                      // 6 KB normalized attention [row][k]

    int blk = blockIdx.x;
    int xcd = blk & 7, slot = blk >> 3;        // slot in [0,192)
    int part = slot / 96, qslot = slot % 96;
    int bh = xcd * 2 + part;
    int b = bh >> 3, h = bh & 7;
    int tid = threadIdx.x;
    int wave = __builtin_amdgcn_readfirstlane(tid >> 6);
    int lane = tid & 63;
    int q0 = qslot * 4;                        // block rows q0 .. q0+3

    // ---- energy: wave = d-chunk `wave`, all 4 rows ----
    const float* eqb = Eq + (size_t)(b * SEQ + q0) * HID + h * HD + wave * 16;
    float g0[16], g1[16], g2[16], g3[16], w[16];
    #pragma unroll
    for (int j = 0; j < 16; ++j) {
        g0[j] = eqb[j];                 // wave-uniform -> scalar loads
        g1[j] = eqb[HID + j];
        g2[j] = eqb[2 * HID + j];
        g3[j] = eqb[3 * HID + j];
        w[j]  = vv2[wave * 16 + j];
    }
    const float4* ekc = (const float4*)Ek4 + (size_t)bh * 16 * SEQ
                      + (size_t)wave * 4 * SEQ + lane;

    float e0[6], e1[6], e2[6], e3[6];
    #pragma unroll
    for (int t = 0; t < 6; ++t) { e0[t] = 0.f; e1[t] = 0.f; e2[t] = 0.f; e3[t] = 0.f; }

    float4 k0 = ekc[0 * SEQ], k1 = ekc[1 * SEQ];
    float4 k2 = ekc[2 * SEQ], k3 = ekc[3 * SEQ];
    #pragma unroll
    for (int kt = 0; kt < 6; ++kt) {
        float4 n0, n1, n2, n3;
        if (kt < 5) {
            const float4* np = ekc + (kt + 1) * 64;
            n0 = np[0 * SEQ]; n1 = np[1 * SEQ];
            n2 = np[2 * SEQ]; n3 = np[3 * SEQ];
        }
        float r0 = e0[kt], r1 = e1[kt], r2 = e2[kt], r3 = e3[kt];
        #define EN(J, KV)                                                      \
        {                                                                      \
            float t0 = __builtin_amdgcn_rcpf(fmaf(g0[J], (KV), 1.f));          \
            float t1 = __builtin_amdgcn_rcpf(fmaf(g1[J], (KV), 1.f));          \
            float t2 = __builtin_amdgcn_rcpf(fmaf(g2[J], (KV), 1.f));          \
            float t3 = __builtin_amdgcn_rcpf(fmaf(g3[J], (KV), 1.f));          \
            r0 = fmaf(w[J], t0, r0);                                           \
            r1 = fmaf(w[J], t1, r1);                                           \
            r2 = fmaf(w[J], t2, r2);                                           \
            r3 = fmaf(w[J], t3, r3);                                           \
        }
        EN(0,  k0.x) EN(1,  k0.y) EN(2,  k0.z) EN(3,  k0.w)
        EN(4,  k1.x) EN(5,  k1.y) EN(6,  k1.z) EN(7,  k1.w)
        EN(8,  k2.x) EN(9,  k2.y) EN(10, k2.z) EN(11, k2.w)
        EN(12, k3.x) EN(13, k3.y) EN(14, k3.z) EN(15, k3.w)
        #undef EN
        e0[kt] = r0; e1[kt] = r1; e2[kt] = r2; e3[kt] = r3;
        k0 = n0; k1 = n1; k2 = n2; k3 = n3;
    }

    #pragma unroll
    for (int t = 0; t < 6; ++t) {
        epart[wave][0][t * 64 + lane] = e0[t];
        epart[wave][1][t * 64 + lane] = e1[t];
        epart[wave][2][t * 64 + lane] = e2[t];
        epart[wave][3][t * 64 + lane] = e3[t];
    }
    __syncthreads();   // B1: all energy partials in LDS

    // Prefetch first 8 V vectors of this wave's k-range (independent of softmax)
    int ko = lane >> 4, d4p = lane & 15;
    const float4* vb = (const float4*)V + (size_t)(b * SEQ) * (HID / 4) + h * 16 + d4p;
    float4 vpre[8];
    #pragma unroll
    for (int i = 0; i < 8; ++i)
        vpre[i] = vb[(size_t)(96 * wave + i * 4 + ko) * (HID / 4)];

    // ---- softmax: wave w owns row w ----
    float e[6];
    #pragma unroll
    for (int t = 0; t < 6; ++t)
        e[t] = (epart[0][wave][t * 64 + lane] + epart[1][wave][t * 64 + lane])
             + (epart[2][wave][t * 64 + lane] + epart[3][wave][t * 64 + lane]);
    float m = e[0];
    #pragma unroll
    for (int t = 1; t < 6; ++t) m = fmaxf(m, e[t]);
    #pragma unroll
    for (int off = 1; off < 64; off <<= 1) m = fmaxf(m, __shfl_xor(m, off));
    float a[6], s = 0.f;
    #pragma unroll
    for (int t = 0; t < 6; ++t) {
        a[t] = __builtin_amdgcn_exp2f((e[t] - m) * SSCL); s += a[t];
    }
    #pragma unroll
    for (int off = 1; off < 64; off <<= 1) s += __shfl_xor(s, off);
    float z = __builtin_amdgcn_rcpf(s);

    size_t abase = (size_t)bh * SEQ * SEQ + (size_t)(q0 + wave) * SEQ;
    #pragma unroll
    for (int t = 0; t < 6; ++t) {
        float av = a[t] * z;
        attnOut[abase + t * 64 + lane] = av;
        aP[wave][t * 64 + lane] = av;
    }
    __syncthreads();   // B2: aP complete; epart free for reuse as xpart

    // ---- attn @ V: wave w covers k in [96w, 96w+96), all 4 rows ----
    float4 x0 = make_float4(0.f, 0.f, 0.f, 0.f);
    float4 x1 = make_float4(0.f, 0.f, 0.f, 0.f);
    float4 x2 = make_float4(0.f, 0.f, 0.f, 0.f);
    float4 x3 = make_float4(0.f, 0.f, 0.f, 0.f);
    #pragma unroll
    for (int i = 0; i < 8; ++i) {
        int k = 96 * wave + i * 4 + ko;
        float4 v = vpre[i];
        float a0 = aP[0][k], a1 = aP[1][k], a2 = aP[2][k], a3 = aP[3][k];
        x0.x = fmaf(a0, v.x, x0.x); x0.y = fmaf(a0, v.y, x0.y);
        x0.z = fmaf(a0, v.z, x0.z); x0.w = fmaf(a0, v.w, x0.w);
        x1.x = fmaf(a1, v.x, x1.x); x1.y = fmaf(a1, v.y, x1.y);
        x1.z = fmaf(a1, v.z, x1.z); x1.w = fmaf(a1, v.w, x1.w);
        x2.x = fmaf(a2, v.x, x2.x); x2.y = fmaf(a2, v.y, x2.y);
        x2.z = fmaf(a2, v.z, x2.z); x2.w = fmaf(a2, v.w, x2.w);
        x3.x = fmaf(a3, v.x, x3.x); x3.y = fmaf(a3, v.y, x3.y);
        x3.z = fmaf(a3, v.z, x3.z); x3.w = fmaf(a3, v.w, x3.w);
    }
    #pragma unroll
    for (int i = 8; i < 24; ++i) {
        int k = 96 * wave + i * 4 + ko;
        float4 v = vb[(size_t)k * (HID / 4)];
        float a0 = aP[0][k], a1 = aP[1][k], a2 = aP[2][k], a3 = aP[3][k];
        x0.x = fmaf(a0, v.x, x0.x); x0.y = fmaf(a0, v.y, x0.y);
        x0.z = fmaf(a0, v.z, x0.z); x0.w = fmaf(a0, v.w, x0.w);
        x1.x = fmaf(a1, v.x, x1.x); x1.y = fmaf(a1, v.y, x1.y);
        x1.z = fmaf(a1, v.z, x1.z); x1.w = fmaf(a1, v.w, x1.w);
        x2.x = fmaf(a2, v.x, x2.x); x2.y = fmaf(a2, v.y, x2.y);
        x2.z = fmaf(a2, v.z, x2.z); x2.w = fmaf(a2, v.w, x2.w);
        x3.x = fmaf(a3, v.x, x3.x); x3.y = fmaf(a3, v.y, x3.y);
        x3.z = fmaf(a3, v.z, x3.z); x3.w = fmaf(a3, v.w, x3.w);
    }
    // reduce over ko (xor butterfly -> every lane holds the k-range total)
    #pragma unroll
    for (int off = 16; off < 64; off <<= 1) {
        x0.x += __shfl_xor(x0.x, off); x0.y += __shfl_xor(x0.y, off);
        x0.z += __shfl_xor(x0.z, off); x0.w += __shfl_xor(x0.w, off);
        x1.x += __shfl_xor(x1.x, off); x1.y += __shfl_xor(x1.y, off);
        x1.z += __shfl_xor(x1.z, off); x1.w += __shfl_xor(x1.w, off);
        x2.x += __shfl_xor(x2.x, off); x2.y += __shfl_xor(x2.y, off);
        x2.z += __shfl_xor(x2.z, off); x2.w += __shfl_xor(x2.w, off);
        x3.x += __shfl_xor(x3.x, off); x3.y += __shfl_xor(x3.y, off);
        x3.z += __shfl_xor(x3.z, off); x3.w += __shfl_xor(x3.w, off);
    }
    float4* xpart = (float4*)&epart[0][0][0];   // [src wave][row][d4p]
    if (lane < 16) {
        xpart[(wave * 4 + 0) * 16 + d4p] = x0;
        xpart[(wave * 4 + 1) * 16 + d4p] = x1;
        xpart[(wave * 4 + 2) * 16 + d4p] = x2;
        xpart[(wave * 4 + 3) * 16 + d4p] = x3;
    }
    __syncthreads();   // B3: PV partials in LDS

    // ---- final: wave w sums row w and packs it into Ax ----
    float4 pa = xpart[(0 * 4 + wave) * 16 + d4p];
    float4 pb = xpart[(1 * 4 + wave) * 16 + d4p];
    float4 pc = xpart[(2 * 4 + wave) * 16 + d4p];
    float4 pd = xpart[(3 * 4 + wave) * 16 + d4p];
    float4 xs;
    xs.x = (pa.x + pb.x) + (pc.x + pd.x);
    xs.y = (pa.y + pb.y) + (pc.y + pd.y);
    xs.z = (pa.z + pb.z) + (pc.z + pd.z);
    xs.w = (pa.w + pb.w) + (pc.w + pd.w);

    // lanes 0..15 hold row (q0+wave) as float4 at d4 = lane; lane u<8 gathers
    // the 8 floats of col-group u from lanes 2u, 2u+1 and writes hi/lo to Ax.
    int u2 = (lane & 7) * 2;
    float f0 = __shfl(xs.x, u2),     f1 = __shfl(xs.y, u2);
    float f2 = __shfl(xs.z, u2),     f3 = __shfl(xs.w, u2);
    float f4 = __shfl(xs.x, u2 + 1), f5 = __shfl(xs.y, u2 + 1);
    float f6 = __shfl(xs.z, u2 + 1), f7 = __shfl(xs.w, u2 + 1);
    if (lane < 8) {
        float vals[8] = {f0, f1, f2, f3, f4, f5, f6, f7};
        int row = b * SEQ + q0 + wave;
        int g = h * 8 + lane;          // global 8-col group
        s8v hi, lo;
        #pragma unroll
        for (int j = 0; j < 8; ++j) {
            unsigned short hh = bf16_rne(vals[j]);
            hi[j] = (short)hh;
            lo[j] = (short)bf16_rne(vals[j] - bf16_val(hh));
        }
        int mt = row >> 4, kt2 = g >> 2;
        int lanei = (row & 15) | ((g & 3) << 4);
        size_t base = ((size_t)mt * 32) * 64 + lanei;
        Ax[base + (size_t)kt2 * 64]        = hi;
        Ax[base + (size_t)(16 + kt2) * 64] = lo;
    }
}

// ---------------------------------------------------------------------------
extern "C" void kernel_launch(void* const* d_in, const int* in_sizes, int n_in,
                              void* d_out, int out_size, void* d_ws, size_t ws_size,
                              hipStream_t stream)
{
    const float* query = (const float*)d_in[0];
    const float* key   = (const float*)d_in[1];
    const float* value = (const float*)d_in[2];
    const float* Wq = (const float*)d_in[3];
    const float* bq = (const float*)d_in[4];
    const float* Wk = (const float*)d_in[5];
    const float* bk = (const float*)d_in[6];
    const float* Wv = (const float*)d_in[7];
    const float* bv = (const float*)d_in[8];
    const float* Ww = (const float*)d_in[9];
    const float* bw = (const float*)d_in[10];
    const float* Wu = (const float*)d_in[11];
    const float* bu = (const float*)d_in[12];
    const float* vv = (const float*)d_in[13];
    const float* Wo = (const float*)d_in[14];
    const float* bo = (const float*)d_in[15];

    float* out_x    = (float*)d_out;                 // [2,384,512]
    float* out_attn = out_x + (size_t)MROWS * HID;   // [2,8,384,384]

    float* ws  = (float*)d_ws;
    float* bqe = ws;                 // 512
    float* bke = bqe + 512;          // 512
    float* vv2 = bke + 512;          // 64
    float* EqB = vv2 + 64;           // 393216
    float* Ek4 = EqB + 393216;       // 393216 (transposed-packed)
    float* Vw  = Ek4 + 393216;       // 393216

    s8v* packs = (s8v*)(Vw + 393216);        // 16B-aligned
    s8v* Aq = packs;                          // APACK_S8 each
    s8v* Ak = Aq + APACK_S8;
    s8v* Av = Ak + APACK_S8;
    s8v* Ax = Av + APACK_S8;
    s8v* Bq = Ax + APACK_S8;                  // BPACK_S8 each
    s8v* Bk = Bq + BPACK_S8;
    s8v* Bv = Bk + BPACK_S8;
    s8v* Bo = Bv + BPACK_S8;

    pack_all_kernel<<<dim3(1089), 256, 0, stream>>>(
        query, key, value,
        Wq, bq, Wk, bk, Wv, Wo, Ww, bw, Wu, bu, vv,
        Aq, Ak, Av, Bq, Bk, Bv, Bo,
        bqe, bke, vv2);
    proj3_mfma_kernel<<<dim3(24, 16, 3), 256, 0, stream>>>(Aq, Ak, Av, Bq, Bk, Bv,
                                                           bqe, bke, bv,
                                                           EqB, Ek4, Vw);
    attn_kernel<<<dim3(1536), 256, 0, stream>>>(EqB, Ek4, Vw, vv2, out_attn, Ax);
    out_mfma_kernel<<<dim3(24, 16), 256, 0, stream>>>(Ax, Bo, bo, out_x);
}

// Round 5
// 141.556 us; speedup vs baseline: 1.1817x; 1.0065x over previous
//
#include <hip/hip_runtime.h>

#define HID 512
#define HEADS 8
#define HD 64
#define BATCH 2
#define SEQ 384
#define MROWS (BATCH * SEQ)  // 768
// 2-section packs: [Ah | Al] and [Bh | Bl], 16 base k-tiles each (K=512)
#define APACK_S8 (48 * 32 * 64)   // 98304 s8-chunks per packed A
#define BPACK_S8 (32 * 32 * 64)   // 65536 s8-chunks per packed B

// 2*log2(e): Eq = exp2(C1 * qW) == exp(2*qW)
#define C1 2.8853900817779268f
// log2(e)/8: softmax exponent scale (energy = raw/8)
#define SSCL 0.18033688011112043f

typedef __attribute__((ext_vector_type(8))) short s8v;      // 8 bf16 (4 VGPR)
typedef __attribute__((ext_vector_type(4))) float f4v;      // MFMA acc
typedef _Float16 h8v __attribute__((ext_vector_type(8)));   // 8 fp16 (16 B)

__device__ __forceinline__ unsigned short bf16_rne(float x) {
    union { float f; unsigned u; } v; v.f = x;
    unsigned r = v.u + 0x7FFFu + ((v.u >> 16) & 1u);
    return (unsigned short)(r >> 16);
}
__device__ __forceinline__ float bf16_val(unsigned short h) {
    union { float f; unsigned u; } v; v.u = ((unsigned)h) << 16; return v.f;
}

// ---------------------------------------------------------------------------
// Pack A [768x512 f32] -> [Ah | Al] bf16 in MFMA swizzle:
// s8 index (mt*32 + sec*16 + kt)*64 + lane, lane = (m&15) | ((g&3)<<4)
// ---------------------------------------------------------------------------
__device__ __forceinline__ void pack_a_one(const float* __restrict__ src,
                                           s8v* __restrict__ dst, int rem)
{
    int g = rem & 63, m = rem >> 6;           // c = 8g .. 8g+7
    const float4* sp = (const float4*)(src + (size_t)m * HID + g * 8);
    float4 v0 = sp[0], v1 = sp[1];
    float vals[8] = {v0.x, v0.y, v0.z, v0.w, v1.x, v1.y, v1.z, v1.w};
    s8v hi, lo;
    #pragma unroll
    for (int j = 0; j < 8; ++j) {
        unsigned short h = bf16_rne(vals[j]);
        hi[j] = (short)h;
        lo[j] = (short)bf16_rne(vals[j] - bf16_val(h));
    }
    int mt = m >> 4, kt = g >> 2;
    int lanei = (m & 15) | ((g & 3) << 4);
    size_t base = ((size_t)mt * 32) * 64 + lanei;
    dst[base + (size_t)kt * 64]        = hi;  // sec0: Ah
    dst[base + (size_t)(16 + kt) * 64] = lo;  // sec1: Al
}

// ---------------------------------------------------------------------------
// Pack W [512x512 f32, (k,n)] -> [Bh | Bl] in MFMA swizzle
// ---------------------------------------------------------------------------
__device__ __forceinline__ void pack_w_store(s8v* __restrict__ dst,
                                             const float vals[8], int kg, int n)
{
    s8v hi, lo;
    #pragma unroll
    for (int j = 0; j < 8; ++j) {
        unsigned short h = bf16_rne(vals[j]);
        hi[j] = (short)h;
        lo[j] = (short)bf16_rne(vals[j] - bf16_val(h));
    }
    int nt = n >> 4, kt = kg >> 2;
    int lanei = (n & 15) | ((kg & 3) << 4);
    size_t base = ((size_t)nt * 32) * 64 + lanei;
    dst[base + (size_t)kt * 64]        = hi;  // sec0: Bh
    dst[base + (size_t)(16 + kt) * 64] = lo;  // sec1: Bl
}

__device__ __forceinline__ void pack_w_one(const float* __restrict__ W,
                                           s8v* __restrict__ dst, int rem)
{
    int kg = rem >> 9, n = rem & 511;         // k = 8kg .. 8kg+7
    float vals[8];
    #pragma unroll
    for (int j = 0; j < 8; ++j)
        vals[j] = W[(size_t)(kg * 8 + j) * HID + n];   // coalesced across n
    pack_w_store(dst, vals, kg, n);
}

// fold Wbig(512x512) @ blockdiag(Wsmall 64x64) on the fly, then pack
__device__ __forceinline__ void fold_pack_w_one(const float* __restrict__ Wbig,
                                                const float* __restrict__ Wsmall,
                                                s8v* __restrict__ dst, int rem)
{
    int kg = __builtin_amdgcn_readfirstlane(rem >> 9);
    int n  = rem & 511;
    int h  = __builtin_amdgcn_readfirstlane(n >> 6);
    int d  = n & 63;
    const float* wr = Wbig + (size_t)(kg * 8) * HID + h * HD;
    float acc[8] = {0.f, 0.f, 0.f, 0.f, 0.f, 0.f, 0.f, 0.f};
    #pragma unroll 8
    for (int t = 0; t < 64; ++t) {
        float wv = Wsmall[t * 64 + d];      // coalesced across lanes
        #pragma unroll
        for (int j = 0; j < 8; ++j)
            acc[j] = fmaf(wr[(size_t)j * HID + t], wv, acc[j]);  // uniform
    }
    pack_w_store(dst, acc, kg, n);
}

// ---------------------------------------------------------------------------
// ONE launch for all prep+pack work (no internal dependencies):
// [0,576): A packs q,k,v | [576,704): Wv | [704,832): Wo
// [832,960): fold(Wq,Ww) | [960,1088): fold(Wk,Wu) | [1088]: biases + vv2
// ---------------------------------------------------------------------------
__global__ __launch_bounds__(256) void pack_all_kernel(
    const float* __restrict__ q, const float* __restrict__ k, const float* __restrict__ v,
    const float* __restrict__ Wq, const float* __restrict__ bq,
    const float* __restrict__ Wk, const float* __restrict__ bk,
    const float* __restrict__ Wv, const float* __restrict__ Wo,
    const float* __restrict__ Ww, const float* __restrict__ bw,
    const float* __restrict__ Wu, const float* __restrict__ bu,
    const float* __restrict__ vv,
    s8v* __restrict__ Aq, s8v* __restrict__ Ak, s8v* __restrict__ Av,
    s8v* __restrict__ Bq, s8v* __restrict__ Bk, s8v* __restrict__ Bv, s8v* __restrict__ Bo,
    float* __restrict__ bqe, float* __restrict__ bke, float* __restrict__ vv2)
{
    int bx = blockIdx.x, tid = threadIdx.x;
    if (bx < 576) {
        int p = bx / 192;
        int rem = (bx % 192) * 256 + tid;
        const float* src = (p == 0) ? q : (p == 1) ? k : v;
        s8v* dst = (p == 0) ? Aq : (p == 1) ? Ak : Av;
        pack_a_one(src, dst, rem);
    } else if (bx < 704) {
        pack_w_one(Wv, Bv, (bx - 576) * 256 + tid);
    } else if (bx < 832) {
        pack_w_one(Wo, Bo, (bx - 704) * 256 + tid);
    } else if (bx < 960) {
        fold_pack_w_one(Wq, Ww, Bq, (bx - 832) * 256 + tid);
    } else if (bx < 1088) {
        fold_pack_w_one(Wk, Wu, Bk, (bx - 960) * 256 + tid);
    } else {
        for (int i = tid; i < 1088; i += 256) {
            if (i < 512) {
                int h = i >> 6, j = i & 63;
                float s = bw[j];
                for (int t = 0; t < 64; ++t) s = fmaf(bq[h * 64 + t], Ww[t * 64 + j], s);
                bqe[i] = s;
            } else if (i < 1024) {
                int n = i - 512, h = n >> 6, j = n & 63;
                float s = bu[j];
                for (int t = 0; t < 64; ++t) s = fmaf(bk[h * 64 + t], Wu[t * 64 + j], s);
                bke[n] = s;
            } else {
                vv2[i - 1024] = -2.0f * vv[i - 1024];
            }
        }
    }
}

// ---------------------------------------------------------------------------
// MFMA GEMM: FOUR waves per block (256 thr), 32x32 tile (2x2 MFMA 16x16x32),
// K-SPLIT across waves; one 16KB LDS exchange + one barrier; each wave
// reduces + writes one acc quadrant.
// MODE 0: plain  MODE 1: exp2(C1*y)
// MODE 2: exp2 -> fp16 Ek, layout half[(((bh*8 + d>>3)*SEQ + k)*8 + (d&7)]
//         (each (bh, d-group-of-8, k) cell = 16 B = one float4 in attn)
// ---------------------------------------------------------------------------
struct Frag { s8v ah0, al0, ah1, al1, bh0, bl0, bh1, bl1; };

__device__ __forceinline__ void load_frag(Frag& f,
    const s8v* __restrict__ a0, const s8v* __restrict__ a1,
    const s8v* __restrict__ b0, const s8v* __restrict__ b1, int kt)
{
    int oh = kt * 64, ol = (16 + kt) * 64;
    f.ah0 = a0[oh]; f.al0 = a0[ol];
    f.ah1 = a1[oh]; f.al1 = a1[ol];
    f.bh0 = b0[oh]; f.bl0 = b0[ol];
    f.bh1 = b1[oh]; f.bl1 = b1[ol];
}

__device__ __forceinline__ void compute_frag(f4v& acc00, f4v& acc01,
                                             f4v& acc10, f4v& acc11, const Frag& f)
{
    acc00 = __builtin_amdgcn_mfma_f32_16x16x32_bf16(f.ah0, f.bh0, acc00, 0, 0, 0);
    acc01 = __builtin_amdgcn_mfma_f32_16x16x32_bf16(f.ah0, f.bh1, acc01, 0, 0, 0);
    acc10 = __builtin_amdgcn_mfma_f32_16x16x32_bf16(f.ah1, f.bh0, acc10, 0, 0, 0);
    acc11 = __builtin_amdgcn_mfma_f32_16x16x32_bf16(f.ah1, f.bh1, acc11, 0, 0, 0);
    acc00 = __builtin_amdgcn_mfma_f32_16x16x32_bf16(f.ah0, f.bl0, acc00, 0, 0, 0);
    acc01 = __builtin_amdgcn_mfma_f32_16x16x32_bf16(f.ah0, f.bl1, acc01, 0, 0, 0);
    acc10 = __builtin_amdgcn_mfma_f32_16x16x32_bf16(f.ah1, f.bl0, acc10, 0, 0, 0);
    acc11 = __builtin_amdgcn_mfma_f32_16x16x32_bf16(f.ah1, f.bl1, acc11, 0, 0, 0);
    acc00 = __builtin_amdgcn_mfma_f32_16x16x32_bf16(f.al0, f.bh0, acc00, 0, 0, 0);
    acc01 = __builtin_amdgcn_mfma_f32_16x16x32_bf16(f.al0, f.bh1, acc01, 0, 0, 0);
    acc10 = __builtin_amdgcn_mfma_f32_16x16x32_bf16(f.al1, f.bh0, acc10, 0, 0, 0);
    acc11 = __builtin_amdgcn_mfma_f32_16x16x32_bf16(f.al1, f.bh1, acc11, 0, 0, 0);
}

template <int MODE>
__device__ __forceinline__ void mfma_gemm_body(
    const s8v* __restrict__ Ap, const s8v* __restrict__ Bp,
    const float* __restrict__ bias, float* __restrict__ out,
    int mt0, int nt0)
{
    __shared__ f4v red[4][4][64];   // [src wave][acc quadrant][lane] = 16 KB

    int tid  = threadIdx.x;
    int wave = __builtin_amdgcn_readfirstlane(tid >> 6);
    int lane = tid & 63;

    const s8v* a0p = Ap + (size_t)(mt0 * 32) * 64 + lane;
    const s8v* a1p = a0p + (size_t)32 * 64;
    const s8v* b0p = Bp + (size_t)(nt0 * 32) * 64 + lane;
    const s8v* b1p = b0p + (size_t)32 * 64;

    f4v acc00 = {0.f, 0.f, 0.f, 0.f};
    f4v acc01 = {0.f, 0.f, 0.f, 0.f};
    f4v acc10 = {0.f, 0.f, 0.f, 0.f};
    f4v acc11 = {0.f, 0.f, 0.f, 0.f};

    // wave w owns base k-tiles 4w .. 4w+3 (each with hi+lo sections)
    int kt0 = wave * 4;
    Frag X, Y;
    load_frag(X, a0p, a1p, b0p, b1p, kt0);
    load_frag(Y, a0p, a1p, b0p, b1p, kt0 + 1);
    compute_frag(acc00, acc01, acc10, acc11, X);
    load_frag(X, a0p, a1p, b0p, b1p, kt0 + 2);
    compute_frag(acc00, acc01, acc10, acc11, Y);
    load_frag(Y, a0p, a1p, b0p, b1p, kt0 + 3);
    compute_frag(acc00, acc01, acc10, acc11, X);
    compute_frag(acc00, acc01, acc10, acc11, Y);

    red[wave][0][lane] = acc00;
    red[wave][1][lane] = acc01;
    red[wave][2][lane] = acc10;
    red[wave][3][lane] = acc11;
    __syncthreads();

    // wave w reduces + writes acc quadrant w:
    // 0 -> (row0,col0)  1 -> (row0,col1)  2 -> (row1,col0)  3 -> (row1,col1)
    f4v s = red[0][wave][lane] + red[1][wave][lane]
          + red[2][wave][lane] + red[3][wave][lane];

    // C/D layout: row = quad*4 + reg, col = lane&15.
    int quad = lane >> 4, c16 = lane & 15;
    int R0 = mt0 * 16 + quad * 4 + (wave >> 1) * 16;
    int C  = nt0 * 16 + c16 + (wave & 1) * 16;
    float biasC = bias[C];

    #pragma unroll
    for (int r = 0; r < 4; ++r) {
        float yy = s[r] + biasC;
        if (MODE != 0) yy = __builtin_amdgcn_exp2f(C1 * yy);
        if (MODE == 2) {
            int ROW = R0 + r;
            int b2 = ROW / SEQ, kk = ROW - b2 * SEQ;
            int hh = C >> 6, dd = C & 63;
            _Float16* o16 = (_Float16*)out;
            o16[((size_t)((b2 * 8 + hh) * 8 + (dd >> 3)) * SEQ + kk) * 8
                + (dd & 7)] = (_Float16)yy;
        } else {
            out[(size_t)(R0 + r) * HID + C] = yy;
        }
    }
}

__global__ __launch_bounds__(256) void proj3_mfma_kernel(
    const s8v* __restrict__ Aq, const s8v* __restrict__ Ak, const s8v* __restrict__ Av,
    const s8v* __restrict__ Bq, const s8v* __restrict__ Bk, const s8v* __restrict__ Bv,
    const float* __restrict__ bqe, const float* __restrict__ bke, const float* __restrict__ bv,
    float* __restrict__ Eq, float* __restrict__ Ek16, float* __restrict__ V)
{
    int p = blockIdx.z;
    int mt0 = blockIdx.x * 2, nt0 = blockIdx.y * 2;
    if (p == 0)      mfma_gemm_body<1>(Aq, Bq, bqe, Eq,   mt0, nt0);
    else if (p == 1) mfma_gemm_body<2>(Ak, Bk, bke, Ek16, mt0, nt0);
    else             mfma_gemm_body<0>(Av, Bv, bv,  V,    mt0, nt0);
}

__global__ __launch_bounds__(256) void out_mfma_kernel(
    const s8v* __restrict__ Ax, const s8v* __restrict__ Bo,
    const float* __restrict__ bo, float* __restrict__ out)
{
    mfma_gemm_body<0>(Ax, Bo, bo, out, blockIdx.x * 2, blockIdx.y * 2);
}

// ---------------------------------------------------------------------------
// attention (R15 = R11 streaming + fp16 Ek):
// 2 q-rows per wave, 768 blocks x 4 waves = 3 blocks/CU, no barriers.
// Ek now fp16: per chunk a wave batches ALL 12 float4 loads (12 outstanding
// VMEM ops vs 4) and converts in-register (v_cvt_f32_f16). Halves the Ek
// L2 stream (604 -> 453 MB total) and halves load-issue count.
// XCD swizzle: xcd = blk & 7; each XCD handles exactly 2 bh slices.
// Rotation: wave w starts at d-chunk w&3 -> decorrelated address streams.
// Eq/vv2 wave-uniform -> scalar. Epilogue packs X directly into Ax.
// ---------------------------------------------------------------------------
__global__ __launch_bounds__(256, 3) void attn_kernel(
    const float* __restrict__ Eq, const _Float16* __restrict__ Ek16,
    const float* __restrict__ V, const float* __restrict__ vv2,
    float* __restrict__ attnOut, s8v* __restrict__ Ax)
{
    __shared__ float2 aP[4][SEQ];

    int blk = blockIdx.x;
    int xcd = blk & 7, slot = blk >> 3;       // slot in [0,96)
    int part = slot / 48, qblk = slot % 48;
    int bh = xcd * 2 + part;
    int b = bh >> 3, h = bh & 7;
    int tid = threadIdx.x;
    int wave = __builtin_amdgcn_readfirstlane(tid >> 6);
    int lane = tid & 63;
    int q0 = qblk * 8 + wave * 2, q1 = q0 + 1;

    const float* eq0 = Eq + (size_t)(b * SEQ + q0) * HID + h * HD;  // uniform
    const float* eq1 = eq0 + HID;
    // fp16 Ek: one float4 = 8 halves = cell (d-group g, k); idx = (bh*8+g)*SEQ + k
    const float4* ekf = (const float4*)Ek16 + (size_t)bh * 8 * SEQ + lane;

    float e0[6], e1[6];
    #pragma unroll
    for (int t = 0; t < 6; ++t) { e0[t] = 0.f; e1[t] = 0.f; }

    #pragma unroll 1
    for (int cc = 0; cc < 4; ++cc) {
        int c = (cc + wave) & 3;          // wave-rotated chunk order (uniform)
        // batch-issue the whole chunk: 12 independent b128 loads in flight
        const float4* p0 = ekf + (size_t)(c * 2) * SEQ;       // d c*16 .. +7
        const float4* p1 = p0 + SEQ;                          // d c*16+8 .. +15
        float4 L0[6], L1[6];
        #pragma unroll
        for (int kt = 0; kt < 6; ++kt) { L0[kt] = p0[kt * 64]; L1[kt] = p1[kt * 64]; }

        float g0[16], g1[16], w[16];
        #pragma unroll
        for (int j = 0; j < 16; ++j) {
            g0[j] = eq0[c * 16 + j];   // wave-uniform -> s_load
            g1[j] = eq1[c * 16 + j];
            w[j]  = vv2[c * 16 + j];
        }
        #pragma unroll
        for (int kt = 0; kt < 6; ++kt) {
            h8v ha = *(h8v*)&L0[kt];
            h8v hb = *(h8v*)&L1[kt];
            float kv[16];
            #pragma unroll
            for (int j = 0; j < 8; ++j) {
                kv[j]     = (float)ha[j];
                kv[8 + j] = (float)hb[j];
            }
            float r0 = e0[kt], r1 = e1[kt];
            #define EN(J)                                                          \
            {                                                                      \
                float t0 = __builtin_amdgcn_rcpf(fmaf(g0[J], kv[J], 1.f));         \
                float t1 = __builtin_amdgcn_rcpf(fmaf(g1[J], kv[J], 1.f));         \
                r0 = fmaf(w[J], t0, r0);                                           \
                r1 = fmaf(w[J], t1, r1);                                           \
            }
            EN(0)  EN(1)  EN(2)  EN(3)  EN(4)  EN(5)  EN(6)  EN(7)
            EN(8)  EN(9)  EN(10) EN(11) EN(12) EN(13) EN(14) EN(15)
            #undef EN
            e0[kt] = r0; e1[kt] = r1;
        }
    }

    // Prefetch first 8 V vectors for the attn@V phase (independent of softmax)
    int ko = lane >> 4, d4p = lane & 15;
    const float4* vb = (const float4*)&V[(size_t)b * SEQ * HID + h * HD + d4p * 4];
    float4 vpre[8];
    #pragma unroll
    for (int i = 0; i < 8; ++i)
        vpre[i] = vb[(size_t)(ko + i * 4) * (HID / 4)];

    // softmax over k (384 = 6 tiles x 64 lanes)
    float m0 = e0[0], m1 = e1[0];
    #pragma unroll
    for (int t = 1; t < 6; ++t) { m0 = fmaxf(m0, e0[t]); m1 = fmaxf(m1, e1[t]); }
    #pragma unroll
    for (int off = 1; off < 64; off <<= 1) {
        m0 = fmaxf(m0, __shfl_xor(m0, off));
        m1 = fmaxf(m1, __shfl_xor(m1, off));
    }
    float a0[6], a1[6], s0 = 0.f, s1 = 0.f;
    #pragma unroll
    for (int t = 0; t < 6; ++t) {
        a0[t] = __builtin_amdgcn_exp2f((e0[t] - m0) * SSCL); s0 += a0[t];
        a1[t] = __builtin_amdgcn_exp2f((e1[t] - m1) * SSCL); s1 += a1[t];
    }
    #pragma unroll
    for (int off = 1; off < 64; off <<= 1) {
        s0 += __shfl_xor(s0, off);
        s1 += __shfl_xor(s1, off);
    }
    float z0 = __builtin_amdgcn_rcpf(s0), z1 = __builtin_amdgcn_rcpf(s1);

    size_t abase = (size_t)bh * SEQ * SEQ + (size_t)q0 * SEQ;
    #pragma unroll
    for (int t = 0; t < 6; ++t) {
        float v0 = a0[t] * z0, v1 = a1[t] * z1;
        attnOut[abase + t * 64 + lane] = v0;
        attnOut[abase + SEQ + t * 64 + lane] = v1;
        aP[wave][t * 64 + lane] = make_float2(v0, v1);
    }
    // no barrier: aP[wave] written and read by the same wave

    // attn @ V: lane = ko*16 + d4p; 4 k-phases, float4 over d, 2 q rows.
    // First 8 iterations use the prefetched vectors.
    float4 x0 = make_float4(0.f, 0.f, 0.f, 0.f);
    float4 x1 = make_float4(0.f, 0.f, 0.f, 0.f);
    #pragma unroll
    for (int i = 0; i < 8; ++i) {
        int k = ko + i * 4;
        float4 v = vpre[i];
        float2 a = aP[wave][k];
        x0.x = fmaf(a.x, v.x, x0.x); x0.y = fmaf(a.x, v.y, x0.y);
        x0.z = fmaf(a.x, v.z, x0.z); x0.w = fmaf(a.x, v.w, x0.w);
        x1.x = fmaf(a.y, v.x, x1.x); x1.y = fmaf(a.y, v.y, x1.y);
        x1.z = fmaf(a.y, v.z, x1.z); x1.w = fmaf(a.y, v.w, x1.w);
    }
    #pragma unroll 8
    for (int k = ko + 32; k < SEQ; k += 4) {
        float4 v = vb[(size_t)k * (HID / 4)];
        float2 a = aP[wave][k];
        x0.x = fmaf(a.x, v.x, x0.x); x0.y = fmaf(a.x, v.y, x0.y);
        x0.z = fmaf(a.x, v.z, x0.z); x0.w = fmaf(a.x, v.w, x0.w);
        x1.x = fmaf(a.y, v.x, x1.x); x1.y = fmaf(a.y, v.y, x1.y);
        x1.z = fmaf(a.y, v.z, x1.z); x1.w = fmaf(a.y, v.w, x1.w);
    }
    #pragma unroll
    for (int off = 16; off < 64; off <<= 1) {
        x0.x += __shfl_xor(x0.x, off); x0.y += __shfl_xor(x0.y, off);
        x0.z += __shfl_xor(x0.z, off); x0.w += __shfl_xor(x0.w, off);
        x1.x += __shfl_xor(x1.x, off); x1.y += __shfl_xor(x1.y, off);
        x1.z += __shfl_xor(x1.z, off); x1.w += __shfl_xor(x1.w, off);
    }

    // Pack X rows q0/q1 (this head's 64 cols) straight into Ax.
    // Lanes 0..15 hold the full row as float4; chunk u (8 floats) = lanes {2u,2u+1}.
    if (ko == 0) {
        float4 p0, p1;
        p0.x = __shfl_xor(x0.x, 1); p0.y = __shfl_xor(x0.y, 1);
        p0.z = __shfl_xor(x0.z, 1); p0.w = __shfl_xor(x0.w, 1);
        p1.x = __shfl_xor(x1.x, 1); p1.y = __shfl_xor(x1.y, 1);
        p1.z = __shfl_xor(x1.z, 1); p1.w = __shfl_xor(x1.w, 1);
        float vals[8];
        int row;
        if ((lane & 1) == 0) {
            vals[0] = x0.x; vals[1] = x0.y; vals[2] = x0.z; vals[3] = x0.w;
            vals[4] = p0.x; vals[5] = p0.y; vals[6] = p0.z; vals[7] = p0.w;
            row = b * SEQ + q0;
        } else {
            vals[0] = p1.x; vals[1] = p1.y; vals[2] = p1.z; vals[3] = p1.w;
            vals[4] = x1.x; vals[5] = x1.y; vals[6] = x1.z; vals[7] = x1.w;
            row = b * SEQ + q1;
        }
        int g = h * 8 + (lane >> 1);   // global 8-col group
        s8v hi, lo;
        #pragma unroll
        for (int j = 0; j < 8; ++j) {
            unsigned short hh = bf16_rne(vals[j]);
            hi[j] = (short)hh;
            lo[j] = (short)bf16_rne(vals[j] - bf16_val(hh));
        }
        int mt = row >> 4, kt2 = g >> 2;
        int lanei = (row & 15) | ((g & 3) << 4);
        size_t base = ((size_t)mt * 32) * 64 + lanei;
        Ax[base + (size_t)kt2 * 64]        = hi;
        Ax[base + (size_t)(16 + kt2) * 64] = lo;
    }
}

// ---------------------------------------------------------------------------
extern "C" void kernel_launch(void* const* d_in, const int* in_sizes, int n_in,
                              void* d_out, int out_size, void* d_ws, size_t ws_size,
                              hipStream_t stream)
{
    const float* query = (const float*)d_in[0];
    const float* key   = (const float*)d_in[1];
    const float* value = (const float*)d_in[2];
    const float* Wq = (const float*)d_in[3];
    const float* bq = (const float*)d_in[4];
    const float* Wk = (const float*)d_in[5];
    const float* bk = (const float*)d_in[6];
    const float* Wv = (const float*)d_in[7];
    const float* bv = (const float*)d_in[8];
    const float* Ww = (const float*)d_in[9];
    const float* bw = (const float*)d_in[10];
    const float* Wu = (const float*)d_in[11];
    const float* bu = (const float*)d_in[12];
    const float* vv = (const float*)d_in[13];
    const float* Wo = (const float*)d_in[14];
    const float* bo = (const float*)d_in[15];

    float* out_x    = (float*)d_out;                 // [2,384,512]
    float* out_attn = out_x + (size_t)MROWS * HID;   // [2,8,384,384]

    float* ws  = (float*)d_ws;
    float* bqe = ws;                 // 512
    float* bke = bqe + 512;          // 512
    float* vv2 = bke + 512;          // 64
    float* EqB = vv2 + 64;           // 393216 floats
    float* Ek16 = EqB + 393216;      // fp16 Ek lives in this (former f32) region
    float* Vw  = Ek16 + 393216;      // 393216 floats

    s8v* packs = (s8v*)(Vw + 393216);        // 16B-aligned
    s8v* Aq = packs;                          // APACK_S8 each
    s8v* Ak = Aq + APACK_S8;
    s8v* Av = Ak + APACK_S8;
    s8v* Ax = Av + APACK_S8;
    s8v* Bq = Ax + APACK_S8;                  // BPACK_S8 each
    s8v* Bk = Bq + BPACK_S8;
    s8v* Bv = Bk + BPACK_S8;
    s8v* Bo = Bv + BPACK_S8;

    pack_all_kernel<<<dim3(1089), 256, 0, stream>>>(
        query, key, value,
        Wq, bq, Wk, bk, Wv, Wo, Ww, bw, Wu, bu, vv,
        Aq, Ak, Av, Bq, Bk, Bv, Bo,
        bqe, bke, vv2);
    proj3_mfma_kernel<<<dim3(24, 16, 3), 256, 0, stream>>>(Aq, Ak, Av, Bq, Bk, Bv,
                                                           bqe, bke, bv,
                                                           EqB, Ek16, Vw);
    attn_kernel<<<dim3(768), 256, 0, stream>>>(EqB, (const _Float16*)Ek16, Vw, vv2,
                                               out_attn, Ax);
    out_mfma_kernel<<<dim3(24, 16), 256, 0, stream>>>(Ax, Bo, bo, out_x);
}